// Round 14
// baseline (265.665 us; speedup 1.0000x reference)
//
#include <hip/hip_runtime.h>
#include <hip/hip_bf16.h>
#include <math.h>

#define NB_B 256
#define NB_S 50
#define NB_NB 8
#define NB_D 128
#define NB_NITEMS 100000

#define C_RZ (-1.442695041f)   // -log2(e): sigmoid arg prescale
#define C_N (2.885390082f)     // 2*log2(e): tanh arg prescale

typedef __attribute__((ext_vector_type(8))) short short8;   // 8 x bf16 (4 VGPR)
typedef __attribute__((ext_vector_type(4))) float f32x4;    // MFMA acc
typedef unsigned int uint;
typedef unsigned short ushort;

// fp32 -> bf16 round-to-nearest-even
__device__ __forceinline__ ushort f2bf(float f) {
  union { float f; uint u; } v;
  v.f = f;
  return (ushort)((v.u + 0x7fffu + ((v.u >> 16) & 1u)) >> 16);
}
__device__ __forceinline__ uint packbf(float a, float b) {
  return (uint)f2bf(a) | ((uint)f2bf(b) << 16);
}
__device__ __forceinline__ float bflo(uint u) {
  union { uint u; float f; } v; v.u = u << 16; return v.f;
}
__device__ __forceinline__ float bfhi(uint u) {
  union { uint u; float f; } v; v.u = u & 0xffff0000u; return v.f;
}
__device__ __forceinline__ float bf2f(ushort u) {
  union { uint u; float f; } v; v.u = (uint)u << 16; return v.f;
}
__device__ __forceinline__ void unpack8(uint4 u, float* f) {
  f[0] = bflo(u.x); f[1] = bfhi(u.x);
  f[2] = bflo(u.y); f[3] = bfhi(u.y);
  f[4] = bflo(u.z); f[5] = bfhi(u.z);
  f[6] = bflo(u.w); f[7] = bfhi(u.w);
}

// ---------------- fused prep: casts + scaled weight transposes + GI bias ----------------
__device__ __forceinline__ void castf_body(const float* __restrict__ src,
                                           uint* __restrict__ dst, int i, int n8) {
  if (i >= n8) return;
  float4 a = ((const float4*)src)[2 * i];
  float4 b = ((const float4*)src)[2 * i + 1];
  uint4 o;
  o.x = packbf(a.x, a.y);
  o.y = packbf(a.z, a.w);
  o.z = packbf(b.x, b.y);
  o.w = packbf(b.z, b.w);
  ((uint4*)dst)[i] = o;
}
template <int CO, bool SCALED>
__device__ __forceinline__ void castT_body(const float* __restrict__ W,
                                           ushort* __restrict__ WT, int idx) {
  if (idx >= 128 * CO) return;
  int n = idx >> 7, k = idx & 127;
  float v = W[(size_t)k * CO + n];
  if (SCALED) v *= (n < 256 ? C_RZ : C_N);
  WT[idx] = f2bf(v);
}
__global__ __launch_bounds__(256) void prep_kernel(
    const float* __restrict__ item_emb, const float* __restrict__ rel_emb,
    const float* __restrict__ Wt, const float* __restrict__ Wih,
    const float* __restrict__ Whh, const float* __restrict__ W2,
    const float* __restrict__ bih, const float* __restrict__ bhh,
    uint* __restrict__ EMB_BF, uint* __restrict__ REL_BF,
    ushort* __restrict__ WtT, ushort* __restrict__ WihT,
    ushort* __restrict__ WhhT, ushort* __restrict__ W2T,
    float* __restrict__ GIBIAS) {
  int bx = blockIdx.x, tid = threadIdx.x;
  if (bx < 6250) {
    castf_body(item_emb, EMB_BF, bx * 256 + tid, 1600000);
  } else if (bx < 6263) {
    castf_body(rel_emb, REL_BF, (bx - 6250) * 256 + tid, 3200);
  } else if (bx < 6327) {
    castT_body<128, false>(Wt, WtT, (bx - 6263) * 256 + tid);
  } else if (bx < 6519) {
    castT_body<384, true>(Wih, WihT, (bx - 6327) * 256 + tid);
  } else if (bx < 6711) {
    castT_body<384, true>(Whh, WhhT, (bx - 6519) * 256 + tid);
  } else if (bx < 6775) {
    castT_body<128, false>(W2, W2T, (bx - 6711) * 256 + tid);
  } else {
    int idx = (bx - 6775) * 256 + tid;
    if (idx < 384) {
      float s = (idx < 256) ? C_RZ : C_N;
      GIBIAS[idx] = s * bih[idx] + (idx < 256 ? s * bhh[idx] : 0.f);
    }
  }
}

// ---------------- pair compute from preloaded registers ----------------
// q = lane&15; us = self row seg, nbp[8] = neighbor row segs, rk[8] = rel ids.
__device__ __forceinline__ uint4 pair_compute(
    uint4 us, const uint4* __restrict__ nbp, const int* __restrict__ rk, int q,
    const uint* __restrict__ relB, const float* __restrict__ Wa,
    float* __restrict__ alds) {
  float s[8], wa[8];
  unpack8(us, s);
  *(float4*)&wa[0] = ((const float4*)Wa)[q * 2];
  *(float4*)&wa[4] = ((const float4*)Wa)[q * 2 + 1];

  float t[8];
#pragma unroll
  for (int k = 0; k < 8; k++) {
    uint4 ur = ((const uint4*)(relB + (size_t)rk[k] * 64))[q];
    float rr[8], nb[8];
    unpack8(ur, rr);
    unpack8(nbp[k], nb);
    float tt = 0.f;
#pragma unroll
    for (int d = 0; d < 8; d++) tt = fmaf(s[d] * wa[d] * rr[d], nb[d], tt);
    t[k] = tt;
  }

  // multi-value halving butterfly within 16 lanes: 8 values -> 1 per lane
  bool b0 = (q & 1), b1 = (q & 2), b2 = (q & 4);
  float a4[4];
#pragma unroll
  for (int i = 0; i < 4; i++) {
    float send = b0 ? t[i] : t[4 + i];
    float recv = __shfl_xor(send, 1);
    a4[i] = (b0 ? t[4 + i] : t[i]) + recv;
  }
  float a2[2];
#pragma unroll
  for (int i = 0; i < 2; i++) {
    float send = b1 ? a4[i] : a4[2 + i];
    float recv = __shfl_xor(send, 2);
    a2[i] = (b1 ? a4[2 + i] : a4[i]) + recv;
  }
  float send1 = b2 ? a2[0] : a2[1];
  float recv1 = __shfl_xor(send1, 4);
  float c = (b2 ? a2[1] : a2[0]) + recv1;
  c += __shfl_xor(c, 8);  // att[k*], k* = (q&1)*4 + (q&2) + ((q&4)>>2)

  // softmax over 8 k-classes (|att|<=~0.04: no max-subtraction needed)
  float e = __expf(c);
  float den = e;
  den += __shfl_xor(den, 1);
  den += __shfl_xor(den, 2);
  den += __shfl_xor(den, 4);
  float alpha = e * __builtin_amdgcn_rcpf(den);

  // broadcast alphas via per-group LDS slot (wave-synchronous)
  int kstar = (q & 1) * 4 + (q & 2) + ((q & 4) >> 2);
  if (q < 8) alds[kstar] = alpha;
  asm volatile("s_waitcnt lgkmcnt(0)" ::: "memory");
  float a8[8];
  *(float4*)&a8[0] = ((const float4*)alds)[0];
  *(float4*)&a8[4] = ((const float4*)alds)[1];

  float x[8];
#pragma unroll
  for (int d = 0; d < 8; d++) x[d] = s[d];
#pragma unroll
  for (int k = 0; k < 8; k++) {
    float nb[8];
    unpack8(nbp[k], nb);
#pragma unroll
    for (int d = 0; d < 8; d++) x[d] = fmaf(a8[k], nb[d], x[d]);
  }
  uint4 o;
  o.x = packbf(x[0], x[1]);
  o.y = packbf(x[2], x[3]);
  o.z = packbf(x[4], x[5]);
  o.w = packbf(x[6], x[7]);
  return o;
}

// ---------------- fused hop0 + lin0, 2-pair software pipeline ----------------
// 3200 blocks x 256 threads, VGPR capped for 4 waves/SIMD. Each 16-lane group
// owns pairs A,B; ALL 18 emb-row gathers + adj rows are issued before pair A's
// compute, so B's gathers hide under A's compute (latency-bound fix, R13 PM).
__global__ __launch_bounds__(256, 4) void hoplin_kernel(
    const int* __restrict__ h_iids, const int* __restrict__ adj_e,
    const int* __restrict__ adj_r, const uint* __restrict__ embB,
    const uint* __restrict__ relB, const float* __restrict__ Wa,
    const ushort* __restrict__ WtT, const float* __restrict__ bt,
    ushort* __restrict__ NEIB) {
  __shared__ ushort X0s[32 * 128];  // XOR-swizzled
  __shared__ float als[16][16];     // [group][pairSlot*8]
  const int bx = blockIdx.x;
  const int wv = threadIdx.x >> 6, ln = threadIdx.x & 63;
  const int g = ln >> 4, q = ln & 15;

  const int lrowA = wv * 8 + g, lrowB = lrowA + 4;
  const int pA = bx * 32 + lrowA, pB = bx * 32 + lrowB;

  // ---- index chains (A and B in parallel) ----
  int bA = pA / (NB_S * NB_NB), mA = pA % (NB_S * NB_NB);
  int bB = pB / (NB_S * NB_NB), mB = pB % (NB_S * NB_NB);
  int hA = h_iids[bA * NB_S + (mA >> 3)];
  int hB = h_iids[bB * NB_S + (mB >> 3)];
  int eA = adj_e[hA * NB_NB + (mA & 7)];
  int eB = adj_e[hB * NB_NB + (mB & 7)];

  // ---- issue ALL row gathers for both pairs ----
  uint4 usA = ((const uint4*)(embB + (size_t)eA * 64))[q];
  uint4 usB = ((const uint4*)(embB + (size_t)eB * 64))[q];
  int4 eaA = ((const int4*)(adj_e + (size_t)eA * 8))[0];
  int4 ebA = ((const int4*)(adj_e + (size_t)eA * 8))[1];
  int4 eaB = ((const int4*)(adj_e + (size_t)eB * 8))[0];
  int4 ebB = ((const int4*)(adj_e + (size_t)eB * 8))[1];
  int4 raA = ((const int4*)(adj_r + (size_t)eA * 8))[0];
  int4 rbA = ((const int4*)(adj_r + (size_t)eA * 8))[1];
  int4 raB = ((const int4*)(adj_r + (size_t)eB * 8))[0];
  int4 rbB = ((const int4*)(adj_r + (size_t)eB * 8))[1];

  int e2A[8] = {eaA.x, eaA.y, eaA.z, eaA.w, ebA.x, ebA.y, ebA.z, ebA.w};
  int e2B[8] = {eaB.x, eaB.y, eaB.z, eaB.w, ebB.x, ebB.y, ebB.z, ebB.w};
  uint4 nbpA[8], nbpB[8];
#pragma unroll
  for (int k = 0; k < 8; k++)
    nbpA[k] = ((const uint4*)(embB + (size_t)e2A[k] * 64))[q];
#pragma unroll
  for (int k = 0; k < 8; k++)
    nbpB[k] = ((const uint4*)(embB + (size_t)e2B[k] * 64))[q];

  int rkA[8] = {raA.x, raA.y, raA.z, raA.w, rbA.x, rbA.y, rbA.z, rbA.w};
  int rkB[8] = {raB.x, raB.y, raB.z, raB.w, rbB.x, rbB.y, rbB.z, rbB.w};

  // ---- compute A (B's gathers still in flight underneath) ----
  {
    uint4 o = pair_compute(usA, nbpA, rkA, q, relB, Wa, &als[wv * 4 + g][0]);
    int byte = (lrowA * 256 + q * 16) ^ ((lrowA & 7) << 4);
    *(uint4*)((char*)X0s + byte) = o;
  }
  // ---- compute B ----
  {
    uint4 o = pair_compute(usB, nbpB, rkB, q, relB, Wa, &als[wv * 4 + g][8]);
    int byte = (lrowB * 256 + q * 16) ^ ((lrowB & 7) << 4);
    *(uint4*)((char*)X0s + byte) = o;
  }
  __syncthreads();

  // ---- MFMA phase: NEIB[32][128] = X0s @ WtT^T + bt ----
  const int lr = ln & 15, lg = ln >> 4;
  short8 afr[2][4];
#pragma unroll
  for (int mf = 0; mf < 2; mf++)
#pragma unroll
    for (int kf = 0; kf < 4; kf++) {
      int row = mf * 16 + lr;
      int byte = (row * 256 + lg * 16 + kf * 64) ^ ((row & 7) << 4);
      afr[mf][kf] = *(const short8*)((const char*)X0s + byte);
    }
  f32x4 acc[2][2] = {};
#pragma unroll
  for (int nf = 0; nf < 2; nf++) {
    int n = (wv * 2 + nf) * 16 + lr;
    const ushort* bb = WtT + (size_t)n * 128 + lg * 8;
#pragma unroll
    for (int kf = 0; kf < 4; kf++) {
      short8 b = *(const short8*)(bb + kf * 32);
#pragma unroll
      for (int mf = 0; mf < 2; mf++)
        acc[mf][nf] = __builtin_amdgcn_mfma_f32_16x16x32_bf16(afr[mf][kf], b,
                                                              acc[mf][nf], 0, 0, 0);
    }
  }
#pragma unroll
  for (int mf = 0; mf < 2; mf++)
#pragma unroll
    for (int nf = 0; nf < 2; nf++) {
      int n = (wv * 2 + nf) * 16 + lr;
      float bv = bt[n];
#pragma unroll
      for (int r = 0; r < 4; r++) {
        int mg = bx * 32 + mf * 16 + lg * 4 + r;
        NEIB[(size_t)mg * 128 + n] = f2bf(acc[mf][nf][r] + bv);
      }
    }
}

// ---------------- hop level 1: 16 pairs/block (dense NEIB reads) ----------------
__global__ __launch_bounds__(256) void hop1_kernel(
    const int* __restrict__ h_iids, const int* __restrict__ adj_e,
    const int* __restrict__ adj_r, const uint* __restrict__ embB,
    const uint* __restrict__ relB, const uint* __restrict__ neibB,
    const float* __restrict__ Wa, uint* __restrict__ Xout) {
  __shared__ float als[16][8];
  const int wv = threadIdx.x >> 6, ln = threadIdx.x & 63;
  const int g = ln >> 4, q = ln & 15;
  int p = blockIdx.x * 16 + wv * 4 + g;
  int e_self = h_iids[p];

  uint4 us = ((const uint4*)(embB + (size_t)e_self * 64))[q];
  int4 ra = ((const int4*)(adj_r + (size_t)e_self * 8))[0];
  int4 rb = ((const int4*)(adj_r + (size_t)e_self * 8))[1];
  int rk[8] = {ra.x, ra.y, ra.z, ra.w, rb.x, rb.y, rb.z, rb.w};
  uint4 nbp[8];
#pragma unroll
  for (int k = 0; k < 8; k++)
    nbp[k] = ((const uint4*)(neibB + ((size_t)p * 8 + k) * 64))[q];

  uint4 o = pair_compute(us, nbp, rk, q, relB, Wa, als[wv * 4 + g]);
  ((uint4*)(Xout + (size_t)p * 64))[q] = o;
}

// ---------------- Y[N,CO] = Xbf[N,128] @ WT_bf^T + bias  (MFMA, no LDS) ----------------
template <int CO, int MPW, bool OUT_BF>
__global__ __launch_bounds__(256) void linm_kernel(
    const ushort* __restrict__ Xbf, const ushort* __restrict__ WT,
    const float* __restrict__ bias, float* __restrict__ Yf,
    ushort* __restrict__ Yb, int nrows) {
  constexpr int NF = CO / 16;
  constexpr int MF = MPW / 16;
  int wave = (int)(blockIdx.x * 4 + (threadIdx.x >> 6));
  int ln = threadIdx.x & 63;
  int m0 = __builtin_amdgcn_readfirstlane(wave) * MPW;
  if (m0 >= nrows) return;
  int lr = ln & 15, lg = ln >> 4;

  short8 afr[MF][4];
#pragma unroll
  for (int mf = 0; mf < MF; mf++) {
    const ushort* ab = Xbf + (size_t)(m0 + mf * 16 + lr) * 128 + lg * 8;
#pragma unroll
    for (int kf = 0; kf < 4; kf++) afr[mf][kf] = *(const short8*)(ab + kf * 32);
  }
  f32x4 acc[MF][NF] = {};
#pragma unroll
  for (int nf = 0; nf < NF; nf++) {
    const ushort* bb = WT + (size_t)(nf * 16 + lr) * 128 + lg * 8;
#pragma unroll
    for (int kf = 0; kf < 4; kf++) {
      short8 b = *(const short8*)(bb + kf * 32);
#pragma unroll
      for (int mf = 0; mf < MF; mf++)
        acc[mf][nf] = __builtin_amdgcn_mfma_f32_16x16x32_bf16(afr[mf][kf], b,
                                                              acc[mf][nf], 0, 0, 0);
    }
  }
#pragma unroll
  for (int mf = 0; mf < MF; mf++)
#pragma unroll
    for (int nf = 0; nf < NF; nf++) {
      int n = nf * 16 + lr;
      float bv = bias[n];
#pragma unroll
      for (int r = 0; r < 4; r++) {
        int m = m0 + mf * 16 + lg * 4 + r;
        float val = acc[mf][nf][r] + bv;
        if (OUT_BF)
          Yb[(size_t)m * CO + n] = f2bf(val);
        else
          Yf[(size_t)m * CO + n] = val;
      }
    }
}

// ---------------- GRU: lane-local gates, depth-3 pipeline, exp2 prescaled ----------------
__global__ __launch_bounds__(512) void gru_mfma_kernel(
    const float* __restrict__ GI, const ushort* __restrict__ WhhT_bf,
    const float* __restrict__ bhh, ushort* __restrict__ OUTB) {
  const int b0 = blockIdx.x * 16;
  const int tid = threadIdx.x;
  const int w = tid >> 6, ln = tid & 63;
  const int lr = ln & 15, lg = ln >> 4;
  const int j = w * 16 + lr;

  __shared__ ushort hA[16 * 128];
  __shared__ ushort hB[16 * 128];

  short8 bfr[3][4];
#pragma unroll
  for (int g = 0; g < 3; g++) {
    const ushort* bb = WhhT_bf + (size_t)(g * 128 + j) * 128 + lg * 8;
#pragma unroll
    for (int kf = 0; kf < 4; kf++) bfr[g][kf] = *(const short8*)(bb + kf * 32);
  }
  const float bhn = C_N * bhh[256 + j];

  float h_reg[4] = {0.f, 0.f, 0.f, 0.f};

  {
    uint* hz = (uint*)hA;
#pragma unroll
    for (int i = tid; i < 1024; i += 512) hz[i] = 0;
  }
  __syncthreads();

  float girA[4][3], girB[4][3], girC[4][3], girD[4][3];
#pragma unroll
  for (int r = 0; r < 4; r++) {
    const float* g0 = GI + ((size_t)(b0 + lg * 4 + r) * NB_S + 0) * 384 + j;
    girA[r][0] = g0[0]; girA[r][1] = g0[128]; girA[r][2] = g0[256];
    const float* g1 = GI + ((size_t)(b0 + lg * 4 + r) * NB_S + 1) * 384 + j;
    girB[r][0] = g1[0]; girB[r][1] = g1[128]; girB[r][2] = g1[256];
    const float* g2 = GI + ((size_t)(b0 + lg * 4 + r) * NB_S + 2) * 384 + j;
    girC[r][0] = g2[0]; girC[r][1] = g2[128]; girC[r][2] = g2[256];
  }

  auto STEP = [&](int t, ushort* hRead, ushort* hWrite, float (&cur)[4][3],
                  float (&pre3)[4][3]) {
    if (t + 3 < NB_S) {
#pragma unroll
      for (int r = 0; r < 4; r++) {
        const float* g = GI + ((size_t)(b0 + lg * 4 + r) * NB_S + (t + 3)) * 384 + j;
        pre3[r][0] = g[0]; pre3[r][1] = g[128]; pre3[r][2] = g[256];
      }
    }
    __builtin_amdgcn_sched_barrier(0);
    short8 afr[4];
#pragma unroll
    for (int kf = 0; kf < 4; kf++) {
      int byte = (lr * 256 + kf * 64 + lg * 16) ^ ((lr & 7) << 4);
      afr[kf] = *(const short8*)((const char*)hRead + byte);
    }
    f32x4 acc[3] = {};
#pragma unroll
    for (int g = 0; g < 3; g++)
#pragma unroll
      for (int kf = 0; kf < 4; kf++)
        acc[g] = __builtin_amdgcn_mfma_f32_16x16x32_bf16(afr[kf], bfr[g][kf],
                                                         acc[g], 0, 0, 0);
#pragma unroll
    for (int r = 0; r < 4; r++) {
      int b = lg * 4 + r;
      float rg = __builtin_amdgcn_rcpf(
          1.f + __builtin_amdgcn_exp2f(cur[r][0] + acc[0][r]));
      float ze = __builtin_amdgcn_exp2f(cur[r][1] + acc[1][r]);
      float xp = cur[r][2] + rg * (bhn + acc[2][r]);
      float e2 = __builtin_amdgcn_exp2f(xp);
      float n = 1.f - 2.f * __builtin_amdgcn_rcpf(e2 + 1.f);
      float h2 = n + (h_reg[r] - n) * __builtin_amdgcn_rcpf(1.f + ze);
      h_reg[r] = h2;
      ushort hb = f2bf(h2);
      OUTB[((size_t)(b0 + b) * NB_S + t) * 128 + j] = hb;
      int byte = (b * 256 + j * 2) ^ ((b & 7) << 4);
      *(ushort*)((char*)hWrite + byte) = hb;
    }
    asm volatile("s_waitcnt lgkmcnt(0)" ::: "memory");
    __builtin_amdgcn_s_barrier();
  };

  for (int g4 = 0; g4 < 12; g4++) {
    int t = g4 * 4;
    STEP(t + 0, hA, hB, girA, girD);
    STEP(t + 1, hB, hA, girB, girA);
    STEP(t + 2, hA, hB, girC, girB);
    STEP(t + 3, hB, hA, girD, girC);
  }
  STEP(48, hA, hB, girA, girD);
  STEP(49, hB, hA, girB, girA);
}

// ---------------- fused pooling (reads bf16 OUTB) ----------------
__global__ __launch_bounds__(256) void pool_kernel(
    const int* __restrict__ h_iids, const ushort* __restrict__ OUTB,
    const float* __restrict__ W1, const float* __restrict__ b1,
    const ushort* __restrict__ W2T, const float* __restrict__ b2,
    const float* __restrict__ W3, const float* __restrict__ Wtr,
    const float* __restrict__ btr, ushort* __restrict__ GHT_bf) {
  const int b = blockIdx.x, tid = threadIdx.x;
  __shared__ float lh[128];
  __shared__ float q1[128];
  __shared__ float al[64];
  __shared__ float cat[256];

  if (tid < 128) {
    int cnt = 0;
    for (int s = 0; s < NB_S; s++) cnt += (h_iids[b * NB_S + s] != 0);
    int li = min(max(cnt - 1, 0), NB_S - 1);
    lh[tid] = bf2f(OUTB[((size_t)b * NB_S + li) * 128 + tid]);
  }
  __syncthreads();
  if (tid < 128) {
    float acc = b1[tid];
    for (int d = 0; d < 128; d++) acc += lh[d] * W1[(size_t)d * 128 + tid];
    q1[tid] = acc;
  }
  __syncthreads();

  {
    const int wv = tid >> 6, ln = tid & 63, lr = ln & 15, lg = ln >> 4;
    const int s0 = wv * 16;
    short8 zz = {0, 0, 0, 0, 0, 0, 0, 0};
    short8 afr[4];
    int srow = s0 + lr;
#pragma unroll
    for (int kf = 0; kf < 4; kf++)
      afr[kf] = (srow < NB_S)
                    ? *(const short8*)(OUTB + ((size_t)b * NB_S + srow) * 128 +
                                       lg * 8 + kf * 32)
                    : zz;
    float part[4] = {0.f, 0.f, 0.f, 0.f};
#pragma unroll
    for (int nf = 0; nf < 8; nf++) {
      const ushort* bb = W2T + (size_t)(nf * 16 + lr) * 128 + lg * 8;
      f32x4 acc = {};
#pragma unroll
      for (int kf = 0; kf < 4; kf++) {
        short8 bv = *(const short8*)(bb + kf * 32);
        acc = __builtin_amdgcn_mfma_f32_16x16x32_bf16(afr[kf], bv, acc, 0, 0, 0);
      }
      int c = nf * 16 + lr;
      float qc = q1[c] + b2[c];
      float w3 = W3[c];
#pragma unroll
      for (int r = 0; r < 4; r++)
        part[r] += w3 / (1.f + __expf(-(qc + acc[r])));
    }
#pragma unroll
    for (int r = 0; r < 4; r++) {
#pragma unroll
      for (int off = 1; off < 16; off <<= 1) part[r] += __shfl_xor(part[r], off);
      int s = s0 + lg * 4 + r;
      if (lr == 0 && s < NB_S) al[s] = part[r];
    }
  }
  __syncthreads();

  if (tid < 128) {
    float g = 0.f;
    for (int s = 0; s < NB_S; s++)
      g += al[s] * bf2f(OUTB[((size_t)b * NB_S + s) * 128 + tid]);
    cat[tid] = lh[tid];
    cat[128 + tid] = g;
  }
  __syncthreads();
  if (tid < 128) {
    float acc = btr[tid];
    for (int dd = 0; dd < 256; dd++) acc += cat[dd] * Wtr[(size_t)dd * 128 + tid];
    GHT_bf[b * 128 + tid] = f2bf(acc);
  }
}

// ---------------- logits = relu(GHT_bf @ EMB_BF^T) via MFMA ----------------
__global__ __launch_bounds__(256) void logits_mfma_kernel(
    const ushort* __restrict__ GHT_bf, const ushort* __restrict__ embB,
    float* __restrict__ out) {
  int wave = (int)(blockIdx.x * 4 + (threadIdx.x >> 6));
  int ln = threadIdx.x & 63;
  int n0 = __builtin_amdgcn_readfirstlane(wave) * 32;
  if (n0 >= NB_NITEMS) return;
  int lr = ln & 15, lg = ln >> 4;

  short8 bfr[2][4];
#pragma unroll
  for (int nf = 0; nf < 2; nf++) {
    const ushort* base = embB + (size_t)(n0 + nf * 16 + lr) * 128 + lg * 8;
#pragma unroll
    for (int kf = 0; kf < 4; kf++) bfr[nf][kf] = *(const short8*)(base + kf * 32);
  }

  f32x4 acc[16][2] = {};
#pragma unroll
  for (int mg = 0; mg < 4; mg++) {
    short8 afr[4][4];
#pragma unroll
    for (int mf = 0; mf < 4; mf++) {
      const ushort* ab = GHT_bf + (size_t)((mg * 4 + mf) * 16 + lr) * 128 + lg * 8;
#pragma unroll
      for (int kf = 0; kf < 4; kf++) afr[mf][kf] = *(const short8*)(ab + kf * 32);
    }
#pragma unroll
    for (int mf = 0; mf < 4; mf++)
#pragma unroll
      for (int nf = 0; nf < 2; nf++)
#pragma unroll
        for (int kf = 0; kf < 4; kf++)
          acc[mg * 4 + mf][nf] = __builtin_amdgcn_mfma_f32_16x16x32_bf16(
              afr[mf][kf], bfr[nf][kf], acc[mg * 4 + mf][nf], 0, 0, 0);
  }

#pragma unroll
  for (int mf = 0; mf < 16; mf++)
#pragma unroll
    for (int nf = 0; nf < 2; nf++) {
      int n = n0 + nf * 16 + lr;
#pragma unroll
      for (int r = 0; r < 4; r++) {
        int m = mf * 16 + lg * 4 + r;
        out[(size_t)m * NB_NITEMS + n] = fmaxf(acc[mf][nf][r], 0.f);
      }
    }
}

extern "C" void kernel_launch(void* const* d_in, const int* in_sizes, int n_in,
                              void* d_out, int out_size, void* d_ws, size_t ws_size,
                              hipStream_t stream) {
  const int* h_iids = (const int*)d_in[0];
  const int* adj_e = (const int*)d_in[2];
  const int* adj_r = (const int*)d_in[3];
  const float* item_emb = (const float*)d_in[4];
  const float* rel_emb = (const float*)d_in[5];
  const float* Wa = (const float*)d_in[6];
  const float* Wt = (const float*)d_in[8];
  const float* bt = (const float*)d_in[9];
  const float* Wih = (const float*)d_in[10];
  const float* Whh = (const float*)d_in[11];
  const float* bih = (const float*)d_in[12];
  const float* bhh = (const float*)d_in[13];
  const float* W1 = (const float*)d_in[14];
  const float* b1 = (const float*)d_in[15];
  const float* W2 = (const float*)d_in[16];
  const float* b2 = (const float*)d_in[17];
  const float* W3 = (const float*)d_in[18];
  const float* Wtr = (const float*)d_in[19];
  const float* btr = (const float*)d_in[20];
  float* out = (float*)d_out;

  // ws layout (bytes), all 16B-aligned. ~79 MB total.
  char* w = (char*)d_ws;
  uint* EMB_BF = (uint*)w;                    w += 25600000;  // 100000x128 bf16
  uint* REL_BF = (uint*)w;                    w += 51200;     // 200x128 bf16
  ushort* WtT_bf = (ushort*)w;                w += 32768;     // [128][128]
  ushort* WihT_bf = (ushort*)w;               w += 98304;     // [384][128] scaled
  ushort* WhhT_bf = (ushort*)w;               w += 98304;     // [384][128] scaled
  ushort* W2T_bf = (ushort*)w;                w += 32768;     // [128][128]
  float* GIBIAS = (float*)w;                  w += 2048;      // 384 floats
  uint* NEIB_bf = (uint*)w;                   w += 26214400;  // 102400x128 bf16
  uint* X1_bf = (uint*)w;                     w += 3276800;   // 12800x128 bf16
  uint* SEQ_bf = (uint*)w;                    w += 3276800;   // 12800x128 bf16
  float* GI = (float*)w;                      w += 19660800;  // 12800x384 fp32
  ushort* GHT_bf = (ushort*)w;                w += 65536;

  // Alias into dead region (recomputed every launch -> replay-safe):
  ushort* OUTB = (ushort*)X1_bf;              // X1_bf dead after SEQ GEMM

  // ---- fused prep (1 launch) ----
  prep_kernel<<<6777, 256, 0, stream>>>(item_emb, rel_emb, Wt, Wih, Whh, W2,
                                        bih, bhh, EMB_BF, REL_BF, WtT_bf,
                                        WihT_bf, WhhT_bf, W2T_bf, GIBIAS);

  // ---- KG hops (hop0 fused with Wt GEMM; X0 never leaves LDS) ----
  hoplin_kernel<<<3200, 256, 0, stream>>>(h_iids, adj_e, adj_r, EMB_BF, REL_BF,
                                          Wa, WtT_bf, bt, (ushort*)NEIB_bf);
  hop1_kernel<<<800, 256, 0, stream>>>(h_iids, adj_e, adj_r, EMB_BF, REL_BF,
                                       NEIB_bf, Wa, X1_bf);
  linm_kernel<128, 32, true><<<100, 256, 0, stream>>>(
      (const ushort*)X1_bf, WtT_bf, bt, nullptr, (ushort*)SEQ_bf, 12800);
  linm_kernel<384, 16, false><<<200, 256, 0, stream>>>(
      (const ushort*)SEQ_bf, WihT_bf, GIBIAS, GI, nullptr, 12800);

  // ---- GRU + fused pooling ----
  gru_mfma_kernel<<<16, 512, 0, stream>>>(GI, WhhT_bf, bhh, OUTB);
  pool_kernel<<<256, 256, 0, stream>>>(h_iids, OUTB, W1, b1, W2T_bf, b2, W3,
                                       Wtr, btr, GHT_bf);

  // ---- logits ----
  logits_mfma_kernel<<<782, 256, 0, stream>>>(GHT_bf, (const ushort*)EMB_BF, out);
}

// Round 15
// 215.310 us; speedup vs baseline: 1.2339x; 1.2339x over previous
//
#include <hip/hip_runtime.h>
#include <hip/hip_bf16.h>
#include <math.h>

#define NB_B 256
#define NB_S 50
#define NB_NB 8
#define NB_D 128
#define NB_NITEMS 100000

#define C_RZ (-1.442695041f)   // -log2(e): sigmoid arg prescale
#define C_N (2.885390082f)     // 2*log2(e): tanh arg prescale

typedef __attribute__((ext_vector_type(8))) short short8;   // 8 x bf16 (4 VGPR)
typedef __attribute__((ext_vector_type(4))) float f32x4;    // MFMA acc
typedef unsigned int uint;
typedef unsigned short ushort;

// fp32 -> bf16 round-to-nearest-even
__device__ __forceinline__ ushort f2bf(float f) {
  union { float f; uint u; } v;
  v.f = f;
  return (ushort)((v.u + 0x7fffu + ((v.u >> 16) & 1u)) >> 16);
}
__device__ __forceinline__ uint packbf(float a, float b) {
  return (uint)f2bf(a) | ((uint)f2bf(b) << 16);
}
__device__ __forceinline__ float bflo(uint u) {
  union { uint u; float f; } v; v.u = u << 16; return v.f;
}
__device__ __forceinline__ float bfhi(uint u) {
  union { uint u; float f; } v; v.u = u & 0xffff0000u; return v.f;
}
__device__ __forceinline__ float bf2f(ushort u) {
  union { uint u; float f; } v; v.u = (uint)u << 16; return v.f;
}
__device__ __forceinline__ void unpack8(uint4 u, float* f) {
  f[0] = bflo(u.x); f[1] = bfhi(u.x);
  f[2] = bflo(u.y); f[3] = bfhi(u.y);
  f[4] = bflo(u.z); f[5] = bfhi(u.z);
  f[6] = bflo(u.w); f[7] = bfhi(u.w);
}

// ---------------- fused prep: casts + scaled weight transposes + GI bias ----------------
__device__ __forceinline__ void castf_body(const float* __restrict__ src,
                                           uint* __restrict__ dst, int i, int n8) {
  if (i >= n8) return;
  float4 a = ((const float4*)src)[2 * i];
  float4 b = ((const float4*)src)[2 * i + 1];
  uint4 o;
  o.x = packbf(a.x, a.y);
  o.y = packbf(a.z, a.w);
  o.z = packbf(b.x, b.y);
  o.w = packbf(b.z, b.w);
  ((uint4*)dst)[i] = o;
}
template <int CO, bool SCALED>
__device__ __forceinline__ void castT_body(const float* __restrict__ W,
                                           ushort* __restrict__ WT, int idx) {
  if (idx >= 128 * CO) return;
  int n = idx >> 7, k = idx & 127;
  float v = W[(size_t)k * CO + n];
  if (SCALED) v *= (n < 256 ? C_RZ : C_N);
  WT[idx] = f2bf(v);
}
__global__ __launch_bounds__(256) void prep_kernel(
    const float* __restrict__ item_emb, const float* __restrict__ rel_emb,
    const float* __restrict__ Wt, const float* __restrict__ Wih,
    const float* __restrict__ Whh, const float* __restrict__ W2,
    const float* __restrict__ bih, const float* __restrict__ bhh,
    uint* __restrict__ EMB_BF, uint* __restrict__ REL_BF,
    ushort* __restrict__ WtT, ushort* __restrict__ WihT,
    ushort* __restrict__ WhhT, ushort* __restrict__ W2T,
    float* __restrict__ GIBIAS) {
  int bx = blockIdx.x, tid = threadIdx.x;
  if (bx < 6250) {
    castf_body(item_emb, EMB_BF, bx * 256 + tid, 1600000);
  } else if (bx < 6263) {
    castf_body(rel_emb, REL_BF, (bx - 6250) * 256 + tid, 3200);
  } else if (bx < 6327) {
    castT_body<128, false>(Wt, WtT, (bx - 6263) * 256 + tid);
  } else if (bx < 6519) {
    castT_body<384, true>(Wih, WihT, (bx - 6327) * 256 + tid);
  } else if (bx < 6711) {
    castT_body<384, true>(Whh, WhhT, (bx - 6519) * 256 + tid);
  } else if (bx < 6775) {
    castT_body<128, false>(W2, W2T, (bx - 6711) * 256 + tid);
  } else {
    int idx = (bx - 6775) * 256 + tid;
    if (idx < 384) {
      float s = (idx < 256) ? C_RZ : C_N;
      GIBIAS[idx] = s * bih[idx] + (idx < 256 ? s * bhh[idx] : 0.f);
    }
  }
}

// ---------------- hop pair: 16-lane group, 8 dims/lane, multi-value reduce ----------------
// (R13 version: loads inside, single pair per call — VGPR-safe.)
__device__ __forceinline__ uint4 hop_pair4(
    int e_self, int q, int p, const int* __restrict__ adj_e,
    const int* __restrict__ adj_r, const uint* __restrict__ embB,
    const uint* __restrict__ relB, const uint* __restrict__ neibB,
    const float* __restrict__ Wa, float* __restrict__ alds) {
  uint4 us = ((const uint4*)(embB + (size_t)e_self * 64))[q];
  float s[8], wa[8], sw[8];
  unpack8(us, s);
  *(float4*)&wa[0] = ((const float4*)Wa)[q * 2];
  *(float4*)&wa[4] = ((const float4*)Wa)[q * 2 + 1];
#pragma unroll
  for (int d = 0; d < 8; d++) sw[d] = s[d] * wa[d];

  int4 ra = ((const int4*)(adj_r + (size_t)e_self * 8))[0];
  int4 rb = ((const int4*)(adj_r + (size_t)e_self * 8))[1];
  int rk[8] = {ra.x, ra.y, ra.z, ra.w, rb.x, rb.y, rb.z, rb.w};

  uint4 nbp[8];
  if (neibB == nullptr) {
    int4 ea = ((const int4*)(adj_e + (size_t)e_self * 8))[0];
    int4 eb = ((const int4*)(adj_e + (size_t)e_self * 8))[1];
    int e2[8] = {ea.x, ea.y, ea.z, ea.w, eb.x, eb.y, eb.z, eb.w};
#pragma unroll
    for (int k = 0; k < 8; k++)
      nbp[k] = ((const uint4*)(embB + (size_t)e2[k] * 64))[q];
  } else {
#pragma unroll
    for (int k = 0; k < 8; k++)
      nbp[k] = ((const uint4*)(neibB + ((size_t)p * 8 + k) * 64))[q];
  }

  float t[8];
#pragma unroll
  for (int k = 0; k < 8; k++) {
    uint4 ur = ((const uint4*)(relB + (size_t)rk[k] * 64))[q];
    float rr[8], nb[8];
    unpack8(ur, rr);
    unpack8(nbp[k], nb);
    float tt = 0.f;
#pragma unroll
    for (int d = 0; d < 8; d++) tt = fmaf(sw[d] * rr[d], nb[d], tt);
    t[k] = tt;
  }

  // multi-value halving butterfly within 16 lanes: 8 values -> 1 per lane
  bool b0 = (q & 1), b1 = (q & 2), b2 = (q & 4);
  float a4[4];
#pragma unroll
  for (int i = 0; i < 4; i++) {
    float send = b0 ? t[i] : t[4 + i];
    float recv = __shfl_xor(send, 1);
    a4[i] = (b0 ? t[4 + i] : t[i]) + recv;
  }
  float a2[2];
#pragma unroll
  for (int i = 0; i < 2; i++) {
    float send = b1 ? a4[i] : a4[2 + i];
    float recv = __shfl_xor(send, 2);
    a2[i] = (b1 ? a4[2 + i] : a4[i]) + recv;
  }
  float send1 = b2 ? a2[0] : a2[1];
  float recv1 = __shfl_xor(send1, 4);
  float c = (b2 ? a2[1] : a2[0]) + recv1;
  c += __shfl_xor(c, 8);  // att[k*], k* = (q&1)*4 + (q&2) + ((q&4)>>2)

  // softmax over 8 k-classes (|att|<=~0.04: no max-subtraction needed)
  float e = __expf(c);
  float den = e;
  den += __shfl_xor(den, 1);
  den += __shfl_xor(den, 2);
  den += __shfl_xor(den, 4);
  float alpha = e * __builtin_amdgcn_rcpf(den);

  // broadcast alphas via per-group LDS slot (wave-synchronous)
  int kstar = (q & 1) * 4 + (q & 2) + ((q & 4) >> 2);
  if (q < 8) alds[kstar] = alpha;
  asm volatile("s_waitcnt lgkmcnt(0)" ::: "memory");
  float a8[8];
  *(float4*)&a8[0] = ((const float4*)alds)[0];
  *(float4*)&a8[4] = ((const float4*)alds)[1];

  float x[8];
#pragma unroll
  for (int d = 0; d < 8; d++) x[d] = s[d];
#pragma unroll
  for (int k = 0; k < 8; k++) {
    float nb[8];
    unpack8(nbp[k], nb);
#pragma unroll
    for (int d = 0; d < 8; d++) x[d] = fmaf(a8[k], nb[d], x[d]);
  }
  uint4 o;
  o.x = packbf(x[0], x[1]);
  o.y = packbf(x[2], x[3]);
  o.z = packbf(x[4], x[5]);
  o.w = packbf(x[6], x[7]);
  return o;
}

// ---------------- fused hop0 + lin0 (R13 version) ----------------
__global__ __launch_bounds__(256) void hoplin_kernel(
    const int* __restrict__ h_iids, const int* __restrict__ adj_e,
    const int* __restrict__ adj_r, const uint* __restrict__ embB,
    const uint* __restrict__ relB, const float* __restrict__ Wa,
    const ushort* __restrict__ WtT, const float* __restrict__ bt,
    ushort* __restrict__ NEIB) {
  __shared__ ushort X0s[32 * 128];  // XOR-swizzled
  __shared__ float als[16][8];
  const int bx = blockIdx.x;
  const int wv = threadIdx.x >> 6, ln = threadIdx.x & 63;
  const int g = ln >> 4, q = ln & 15;
  float* alds = als[wv * 4 + g];

#pragma unroll
  for (int it = 0; it < 2; it++) {
    int lrow = wv * 8 + it * 4 + g;
    int p = bx * 32 + lrow;
    int b = p / (NB_S * NB_NB);
    int m = p % (NB_S * NB_NB);
    int s = m >> 3, jj = m & 7;
    int h = h_iids[b * NB_S + s];
    int e_self = adj_e[h * NB_NB + jj];
    uint4 o = hop_pair4(e_self, q, p, adj_e, adj_r, embB, relB, nullptr, Wa, alds);
    int byte = (lrow * 256 + q * 16) ^ ((lrow & 7) << 4);
    *(uint4*)((char*)X0s + byte) = o;
  }
  __syncthreads();

  const int lr = ln & 15, lg = ln >> 4;
  short8 afr[2][4];
#pragma unroll
  for (int mf = 0; mf < 2; mf++)
#pragma unroll
    for (int kf = 0; kf < 4; kf++) {
      int row = mf * 16 + lr;
      int byte = (row * 256 + lg * 16 + kf * 64) ^ ((row & 7) << 4);
      afr[mf][kf] = *(const short8*)((const char*)X0s + byte);
    }
  f32x4 acc[2][2] = {};
#pragma unroll
  for (int nf = 0; nf < 2; nf++) {
    int n = (wv * 2 + nf) * 16 + lr;
    const ushort* bb = WtT + (size_t)n * 128 + lg * 8;
#pragma unroll
    for (int kf = 0; kf < 4; kf++) {
      short8 b = *(const short8*)(bb + kf * 32);
#pragma unroll
      for (int mf = 0; mf < 2; mf++)
        acc[mf][nf] = __builtin_amdgcn_mfma_f32_16x16x32_bf16(afr[mf][kf], b,
                                                              acc[mf][nf], 0, 0, 0);
    }
  }
#pragma unroll
  for (int mf = 0; mf < 2; mf++)
#pragma unroll
    for (int nf = 0; nf < 2; nf++) {
      int n = (wv * 2 + nf) * 16 + lr;
      float bv = bt[n];
#pragma unroll
      for (int r = 0; r < 4; r++) {
        int mg = bx * 32 + mf * 16 + lg * 4 + r;
        NEIB[(size_t)mg * 128 + n] = f2bf(acc[mf][nf][r] + bv);
      }
    }
}

// ---------------- fused hop1 + SEQ GEMM + GI GEMM ----------------
// 800 blocks x 256 threads. Phase 1: 16 pairs -> X1 in swizzled LDS.
// Phase 2: SEQ[16][128] = X1 @ WtT^T + bt -> swizzled LDS (bf16).
// Phase 3: GI[16][384] = SEQ @ WihT^T + GIBIAS -> global fp32.
__global__ __launch_bounds__(256) void hopgi_kernel(
    const int* __restrict__ h_iids, const int* __restrict__ adj_e,
    const int* __restrict__ adj_r, const uint* __restrict__ embB,
    const uint* __restrict__ relB, const uint* __restrict__ neibB,
    const float* __restrict__ Wa, const ushort* __restrict__ WtT,
    const float* __restrict__ bt, const ushort* __restrict__ WihT,
    const float* __restrict__ GIBIAS, float* __restrict__ GI) {
  __shared__ ushort X1s[16 * 128];  // XOR-swizzled
  __shared__ ushort SEQs[16 * 128]; // XOR-swizzled
  __shared__ float als[16][8];
  const int wv = threadIdx.x >> 6, ln = threadIdx.x & 63;
  const int g = ln >> 4, q = ln & 15;
  const int lp = wv * 4 + g;  // local pair 0..15
  const int p = blockIdx.x * 16 + lp;

  int e_self = h_iids[p];
  uint4 o = hop_pair4(e_self, q, p, adj_e, adj_r, embB, relB, neibB, Wa, als[lp]);
  {
    int byte = (lp * 256 + q * 16) ^ ((lp & 7) << 4);
    *(uint4*)((char*)X1s + byte) = o;
  }
  __syncthreads();

  const int lr = ln & 15, lg = ln >> 4;
  // phase 2: SEQ = X1 @ WtT + bt; wave covers cols [wv*32, wv*32+32)
  {
    short8 afr[4];
#pragma unroll
    for (int kf = 0; kf < 4; kf++) {
      int byte = (lr * 256 + lg * 16 + kf * 64) ^ ((lr & 7) << 4);
      afr[kf] = *(const short8*)((const char*)X1s + byte);
    }
    f32x4 acc[2] = {};
#pragma unroll
    for (int nf = 0; nf < 2; nf++) {
      int n = (wv * 2 + nf) * 16 + lr;
      const ushort* bb = WtT + (size_t)n * 128 + lg * 8;
#pragma unroll
      for (int kf = 0; kf < 4; kf++) {
        short8 b = *(const short8*)(bb + kf * 32);
        acc[nf] = __builtin_amdgcn_mfma_f32_16x16x32_bf16(afr[kf], b, acc[nf],
                                                          0, 0, 0);
      }
    }
#pragma unroll
    for (int nf = 0; nf < 2; nf++) {
      int n = (wv * 2 + nf) * 16 + lr;
      float bv = bt[n];
#pragma unroll
      for (int r = 0; r < 4; r++) {
        int m = lg * 4 + r;
        int byte = (m * 256 + n * 2) ^ ((m & 7) << 4);
        *(ushort*)((char*)SEQs + byte) = f2bf(acc[nf][r] + bv);
      }
    }
  }
  __syncthreads();

  // phase 3: GI = SEQ @ WihT + GIBIAS; wave covers cols [wv*96, wv*96+96)
  {
    short8 sfr[4];
#pragma unroll
    for (int kf = 0; kf < 4; kf++) {
      int byte = (lr * 256 + lg * 16 + kf * 64) ^ ((lr & 7) << 4);
      sfr[kf] = *(const short8*)((const char*)SEQs + byte);
    }
#pragma unroll
    for (int i = 0; i < 6; i++) {
      int n = (wv * 6 + i) * 16 + lr;
      const ushort* bb = WihT + (size_t)n * 128 + lg * 8;
      f32x4 a2 = {};
#pragma unroll
      for (int kf = 0; kf < 4; kf++) {
        short8 b = *(const short8*)(bb + kf * 32);
        a2 = __builtin_amdgcn_mfma_f32_16x16x32_bf16(sfr[kf], b, a2, 0, 0, 0);
      }
      float bv = GIBIAS[n];
#pragma unroll
      for (int r = 0; r < 4; r++) {
        int m = lg * 4 + r;
        GI[(size_t)(blockIdx.x * 16 + m) * 384 + n] = a2[r] + bv;
      }
    }
  }
}

// ---------------- GRU: lane-local gates, depth-3 pipeline, exp2 prescaled ----------------
__global__ __launch_bounds__(512) void gru_mfma_kernel(
    const float* __restrict__ GI, const ushort* __restrict__ WhhT_bf,
    const float* __restrict__ bhh, ushort* __restrict__ OUTB) {
  const int b0 = blockIdx.x * 16;
  const int tid = threadIdx.x;
  const int w = tid >> 6, ln = tid & 63;
  const int lr = ln & 15, lg = ln >> 4;
  const int j = w * 16 + lr;

  __shared__ ushort hA[16 * 128];
  __shared__ ushort hB[16 * 128];

  short8 bfr[3][4];
#pragma unroll
  for (int g = 0; g < 3; g++) {
    const ushort* bb = WhhT_bf + (size_t)(g * 128 + j) * 128 + lg * 8;
#pragma unroll
    for (int kf = 0; kf < 4; kf++) bfr[g][kf] = *(const short8*)(bb + kf * 32);
  }
  const float bhn = C_N * bhh[256 + j];

  float h_reg[4] = {0.f, 0.f, 0.f, 0.f};

  {
    uint* hz = (uint*)hA;
#pragma unroll
    for (int i = tid; i < 1024; i += 512) hz[i] = 0;
  }
  __syncthreads();

  float girA[4][3], girB[4][3], girC[4][3], girD[4][3];
#pragma unroll
  for (int r = 0; r < 4; r++) {
    const float* g0 = GI + ((size_t)(b0 + lg * 4 + r) * NB_S + 0) * 384 + j;
    girA[r][0] = g0[0]; girA[r][1] = g0[128]; girA[r][2] = g0[256];
    const float* g1 = GI + ((size_t)(b0 + lg * 4 + r) * NB_S + 1) * 384 + j;
    girB[r][0] = g1[0]; girB[r][1] = g1[128]; girB[r][2] = g1[256];
    const float* g2 = GI + ((size_t)(b0 + lg * 4 + r) * NB_S + 2) * 384 + j;
    girC[r][0] = g2[0]; girC[r][1] = g2[128]; girC[r][2] = g2[256];
  }

  auto STEP = [&](int t, ushort* hRead, ushort* hWrite, float (&cur)[4][3],
                  float (&pre3)[4][3]) {
    if (t + 3 < NB_S) {
#pragma unroll
      for (int r = 0; r < 4; r++) {
        const float* g = GI + ((size_t)(b0 + lg * 4 + r) * NB_S + (t + 3)) * 384 + j;
        pre3[r][0] = g[0]; pre3[r][1] = g[128]; pre3[r][2] = g[256];
      }
    }
    __builtin_amdgcn_sched_barrier(0);
    short8 afr[4];
#pragma unroll
    for (int kf = 0; kf < 4; kf++) {
      int byte = (lr * 256 + kf * 64 + lg * 16) ^ ((lr & 7) << 4);
      afr[kf] = *(const short8*)((const char*)hRead + byte);
    }
    f32x4 acc[3] = {};
#pragma unroll
    for (int g = 0; g < 3; g++)
#pragma unroll
      for (int kf = 0; kf < 4; kf++)
        acc[g] = __builtin_amdgcn_mfma_f32_16x16x32_bf16(afr[kf], bfr[g][kf],
                                                         acc[g], 0, 0, 0);
#pragma unroll
    for (int r = 0; r < 4; r++) {
      int b = lg * 4 + r;
      float rg = __builtin_amdgcn_rcpf(
          1.f + __builtin_amdgcn_exp2f(cur[r][0] + acc[0][r]));
      float ze = __builtin_amdgcn_exp2f(cur[r][1] + acc[1][r]);
      float xp = cur[r][2] + rg * (bhn + acc[2][r]);
      float e2 = __builtin_amdgcn_exp2f(xp);
      float n = 1.f - 2.f * __builtin_amdgcn_rcpf(e2 + 1.f);
      float h2 = n + (h_reg[r] - n) * __builtin_amdgcn_rcpf(1.f + ze);
      h_reg[r] = h2;
      ushort hb = f2bf(h2);
      OUTB[((size_t)(b0 + b) * NB_S + t) * 128 + j] = hb;
      int byte = (b * 256 + j * 2) ^ ((b & 7) << 4);
      *(ushort*)((char*)hWrite + byte) = hb;
    }
    asm volatile("s_waitcnt lgkmcnt(0)" ::: "memory");
    __builtin_amdgcn_s_barrier();
  };

  for (int g4 = 0; g4 < 12; g4++) {
    int t = g4 * 4;
    STEP(t + 0, hA, hB, girA, girD);
    STEP(t + 1, hB, hA, girB, girA);
    STEP(t + 2, hA, hB, girC, girB);
    STEP(t + 3, hB, hA, girD, girC);
  }
  STEP(48, hA, hB, girA, girD);
  STEP(49, hB, hA, girB, girA);
}

// ---------------- fused pooling (reads bf16 OUTB) ----------------
__global__ __launch_bounds__(256) void pool_kernel(
    const int* __restrict__ h_iids, const ushort* __restrict__ OUTB,
    const float* __restrict__ W1, const float* __restrict__ b1,
    const ushort* __restrict__ W2T, const float* __restrict__ b2,
    const float* __restrict__ W3, const float* __restrict__ Wtr,
    const float* __restrict__ btr, ushort* __restrict__ GHT_bf) {
  const int b = blockIdx.x, tid = threadIdx.x;
  __shared__ float lh[128];
  __shared__ float q1[128];
  __shared__ float al[64];
  __shared__ float cat[256];

  if (tid < 128) {
    int cnt = 0;
    for (int s = 0; s < NB_S; s++) cnt += (h_iids[b * NB_S + s] != 0);
    int li = min(max(cnt - 1, 0), NB_S - 1);
    lh[tid] = bf2f(OUTB[((size_t)b * NB_S + li) * 128 + tid]);
  }
  __syncthreads();
  if (tid < 128) {
    float acc = b1[tid];
    for (int d = 0; d < 128; d++) acc += lh[d] * W1[(size_t)d * 128 + tid];
    q1[tid] = acc;
  }
  __syncthreads();

  {
    const int wv = tid >> 6, ln = tid & 63, lr = ln & 15, lg = ln >> 4;
    const int s0 = wv * 16;
    short8 zz = {0, 0, 0, 0, 0, 0, 0, 0};
    short8 afr[4];
    int srow = s0 + lr;
#pragma unroll
    for (int kf = 0; kf < 4; kf++)
      afr[kf] = (srow < NB_S)
                    ? *(const short8*)(OUTB + ((size_t)b * NB_S + srow) * 128 +
                                       lg * 8 + kf * 32)
                    : zz;
    float part[4] = {0.f, 0.f, 0.f, 0.f};
#pragma unroll
    for (int nf = 0; nf < 8; nf++) {
      const ushort* bb = W2T + (size_t)(nf * 16 + lr) * 128 + lg * 8;
      f32x4 acc = {};
#pragma unroll
      for (int kf = 0; kf < 4; kf++) {
        short8 bv = *(const short8*)(bb + kf * 32);
        acc = __builtin_amdgcn_mfma_f32_16x16x32_bf16(afr[kf], bv, acc, 0, 0, 0);
      }
      int c = nf * 16 + lr;
      float qc = q1[c] + b2[c];
      float w3 = W3[c];
#pragma unroll
      for (int r = 0; r < 4; r++)
        part[r] += w3 / (1.f + __expf(-(qc + acc[r])));
    }
#pragma unroll
    for (int r = 0; r < 4; r++) {
#pragma unroll
      for (int off = 1; off < 16; off <<= 1) part[r] += __shfl_xor(part[r], off);
      int s = s0 + lg * 4 + r;
      if (lr == 0 && s < NB_S) al[s] = part[r];
    }
  }
  __syncthreads();

  if (tid < 128) {
    float g = 0.f;
    for (int s = 0; s < NB_S; s++)
      g += al[s] * bf2f(OUTB[((size_t)b * NB_S + s) * 128 + tid]);
    cat[tid] = lh[tid];
    cat[128 + tid] = g;
  }
  __syncthreads();
  if (tid < 128) {
    float acc = btr[tid];
    for (int dd = 0; dd < 256; dd++) acc += cat[dd] * Wtr[(size_t)dd * 128 + tid];
    GHT_bf[b * 128 + tid] = f2bf(acc);
  }
}

// ---------------- logits = relu(GHT_bf @ EMB_BF^T) via MFMA ----------------
__global__ __launch_bounds__(256) void logits_mfma_kernel(
    const ushort* __restrict__ GHT_bf, const ushort* __restrict__ embB,
    float* __restrict__ out) {
  int wave = (int)(blockIdx.x * 4 + (threadIdx.x >> 6));
  int ln = threadIdx.x & 63;
  int n0 = __builtin_amdgcn_readfirstlane(wave) * 32;
  if (n0 >= NB_NITEMS) return;
  int lr = ln & 15, lg = ln >> 4;

  short8 bfr[2][4];
#pragma unroll
  for (int nf = 0; nf < 2; nf++) {
    const ushort* base = embB + (size_t)(n0 + nf * 16 + lr) * 128 + lg * 8;
#pragma unroll
    for (int kf = 0; kf < 4; kf++) bfr[nf][kf] = *(const short8*)(base + kf * 32);
  }

  f32x4 acc[16][2] = {};
#pragma unroll
  for (int mg = 0; mg < 4; mg++) {
    short8 afr[4][4];
#pragma unroll
    for (int mf = 0; mf < 4; mf++) {
      const ushort* ab = GHT_bf + (size_t)((mg * 4 + mf) * 16 + lr) * 128 + lg * 8;
#pragma unroll
      for (int kf = 0; kf < 4; kf++) afr[mf][kf] = *(const short8*)(ab + kf * 32);
    }
#pragma unroll
    for (int mf = 0; mf < 4; mf++)
#pragma unroll
      for (int nf = 0; nf < 2; nf++)
#pragma unroll
        for (int kf = 0; kf < 4; kf++)
          acc[mg * 4 + mf][nf] = __builtin_amdgcn_mfma_f32_16x16x32_bf16(
              afr[mf][kf], bfr[nf][kf], acc[mg * 4 + mf][nf], 0, 0, 0);
  }

#pragma unroll
  for (int mf = 0; mf < 16; mf++)
#pragma unroll
    for (int nf = 0; nf < 2; nf++) {
      int n = n0 + nf * 16 + lr;
#pragma unroll
      for (int r = 0; r < 4; r++) {
        int m = mf * 16 + lg * 4 + r;
        out[(size_t)m * NB_NITEMS + n] = fmaxf(acc[mf][nf][r], 0.f);
      }
    }
}

extern "C" void kernel_launch(void* const* d_in, const int* in_sizes, int n_in,
                              void* d_out, int out_size, void* d_ws, size_t ws_size,
                              hipStream_t stream) {
  const int* h_iids = (const int*)d_in[0];
  const int* adj_e = (const int*)d_in[2];
  const int* adj_r = (const int*)d_in[3];
  const float* item_emb = (const float*)d_in[4];
  const float* rel_emb = (const float*)d_in[5];
  const float* Wa = (const float*)d_in[6];
  const float* Wt = (const float*)d_in[8];
  const float* bt = (const float*)d_in[9];
  const float* Wih = (const float*)d_in[10];
  const float* Whh = (const float*)d_in[11];
  const float* bih = (const float*)d_in[12];
  const float* bhh = (const float*)d_in[13];
  const float* W1 = (const float*)d_in[14];
  const float* b1 = (const float*)d_in[15];
  const float* W2 = (const float*)d_in[16];
  const float* b2 = (const float*)d_in[17];
  const float* W3 = (const float*)d_in[18];
  const float* Wtr = (const float*)d_in[19];
  const float* btr = (const float*)d_in[20];
  float* out = (float*)d_out;

  // ws layout (bytes), all 16B-aligned. ~76 MB total.
  char* w = (char*)d_ws;
  uint* EMB_BF = (uint*)w;                    w += 25600000;  // 100000x128 bf16
  uint* REL_BF = (uint*)w;                    w += 51200;     // 200x128 bf16
  ushort* WtT_bf = (ushort*)w;                w += 32768;     // [128][128]
  ushort* WihT_bf = (ushort*)w;               w += 98304;     // [384][128] scaled
  ushort* WhhT_bf = (ushort*)w;               w += 98304;     // [384][128] scaled
  ushort* W2T_bf = (ushort*)w;                w += 32768;     // [128][128]
  float* GIBIAS = (float*)w;                  w += 2048;      // 384 floats
  uint* NEIB_bf = (uint*)w;                   w += 26214400;  // 102400x128 bf16
  float* GI = (float*)w;                      w += 19660800;  // 12800x384 fp32
  ushort* OUTB = (ushort*)w;                  w += 3276800;   // 12800x128 bf16
  ushort* GHT_bf = (ushort*)w;                w += 65536;

  // ---- fused prep (1 launch) ----
  prep_kernel<<<6777, 256, 0, stream>>>(item_emb, rel_emb, Wt, Wih, Whh, W2,
                                        bih, bhh, EMB_BF, REL_BF, WtT_bf,
                                        WihT_bf, WhhT_bf, W2T_bf, GIBIAS);

  // ---- KG hops (hop0+Wt fused; hop1+Wt+Wih fused) ----
  hoplin_kernel<<<3200, 256, 0, stream>>>(h_iids, adj_e, adj_r, EMB_BF, REL_BF,
                                          Wa, WtT_bf, bt, (ushort*)NEIB_bf);
  hopgi_kernel<<<800, 256, 0, stream>>>(h_iids, adj_e, adj_r, EMB_BF, REL_BF,
                                        NEIB_bf, Wa, WtT_bf, bt, WihT_bf,
                                        GIBIAS, GI);

  // ---- GRU + fused pooling ----
  gru_mfma_kernel<<<16, 512, 0, stream>>>(GI, WhhT_bf, bhh, OUTB);
  pool_kernel<<<256, 256, 0, stream>>>(h_iids, OUTB, W1, b1, W2T_bf, b2, W3,
                                       Wtr, btr, GHT_bf);

  // ---- logits ----
  logits_mfma_kernel<<<782, 256, 0, stream>>>(GHT_bf, (const ushort*)EMB_BF, out);
}

// Round 16
// 213.874 us; speedup vs baseline: 1.2422x; 1.0067x over previous
//
#include <hip/hip_runtime.h>
#include <hip/hip_bf16.h>
#include <math.h>

#define NB_B 256
#define NB_S 50
#define NB_NB 8
#define NB_D 128
#define NB_NITEMS 100000

#define C_RZ (-1.442695041f)   // -log2(e): sigmoid arg prescale
#define C_N (2.885390082f)     // 2*log2(e): tanh arg prescale

typedef __attribute__((ext_vector_type(8))) short short8;   // 8 x bf16 (4 VGPR)
typedef __attribute__((ext_vector_type(4))) float f32x4;    // MFMA acc
typedef unsigned int uint;
typedef unsigned short ushort;

// fp32 -> bf16 round-to-nearest-even
__device__ __forceinline__ ushort f2bf(float f) {
  union { float f; uint u; } v;
  v.f = f;
  return (ushort)((v.u + 0x7fffu + ((v.u >> 16) & 1u)) >> 16);
}
__device__ __forceinline__ uint packbf(float a, float b) {
  return (uint)f2bf(a) | ((uint)f2bf(b) << 16);
}
__device__ __forceinline__ float bflo(uint u) {
  union { uint u; float f; } v; v.u = u << 16; return v.f;
}
__device__ __forceinline__ float bfhi(uint u) {
  union { uint u; float f; } v; v.u = u & 0xffff0000u; return v.f;
}
__device__ __forceinline__ float bf2f(ushort u) {
  union { uint u; float f; } v; v.u = (uint)u << 16; return v.f;
}
__device__ __forceinline__ void unpack8(uint4 u, float* f) {
  f[0] = bflo(u.x); f[1] = bfhi(u.x);
  f[2] = bflo(u.y); f[3] = bfhi(u.y);
  f[4] = bflo(u.z); f[5] = bfhi(u.z);
  f[6] = bflo(u.w); f[7] = bfhi(u.w);
}

// ---------------- fused prep: casts + scaled weight transposes + GI bias ----------------
__device__ __forceinline__ void castf_body(const float* __restrict__ src,
                                           uint* __restrict__ dst, int i, int n8) {
  if (i >= n8) return;
  float4 a = ((const float4*)src)[2 * i];
  float4 b = ((const float4*)src)[2 * i + 1];
  uint4 o;
  o.x = packbf(a.x, a.y);
  o.y = packbf(a.z, a.w);
  o.z = packbf(b.x, b.y);
  o.w = packbf(b.z, b.w);
  ((uint4*)dst)[i] = o;
}
template <int CO, bool SCALED>
__device__ __forceinline__ void castT_body(const float* __restrict__ W,
                                           ushort* __restrict__ WT, int idx) {
  if (idx >= 128 * CO) return;
  int n = idx >> 7, k = idx & 127;
  float v = W[(size_t)k * CO + n];
  if (SCALED) v *= (n < 256 ? C_RZ : C_N);
  WT[idx] = f2bf(v);
}
__global__ __launch_bounds__(256) void prep_kernel(
    const float* __restrict__ item_emb, const float* __restrict__ rel_emb,
    const float* __restrict__ Wt, const float* __restrict__ Wih,
    const float* __restrict__ Whh, const float* __restrict__ W2,
    const float* __restrict__ bih, const float* __restrict__ bhh,
    uint* __restrict__ EMB_BF, uint* __restrict__ REL_BF,
    ushort* __restrict__ WtT, ushort* __restrict__ WihT,
    ushort* __restrict__ WhhT, ushort* __restrict__ W2T,
    float* __restrict__ GIBIAS) {
  int bx = blockIdx.x, tid = threadIdx.x;
  if (bx < 6250) {
    castf_body(item_emb, EMB_BF, bx * 256 + tid, 1600000);
  } else if (bx < 6263) {
    castf_body(rel_emb, REL_BF, (bx - 6250) * 256 + tid, 3200);
  } else if (bx < 6327) {
    castT_body<128, false>(Wt, WtT, (bx - 6263) * 256 + tid);
  } else if (bx < 6519) {
    castT_body<384, true>(Wih, WihT, (bx - 6327) * 256 + tid);
  } else if (bx < 6711) {
    castT_body<384, true>(Whh, WhhT, (bx - 6519) * 256 + tid);
  } else if (bx < 6775) {
    castT_body<128, false>(W2, W2T, (bx - 6711) * 256 + tid);
  } else {
    int idx = (bx - 6775) * 256 + tid;
    if (idx < 384) {
      float s = (idx < 256) ? C_RZ : C_N;
      GIBIAS[idx] = s * bih[idx] + (idx < 256 ? s * bhh[idx] : 0.f);
    }
  }
}

// ---------------- hop pair: 16-lane group, 8 dims/lane, multi-value reduce ----------------
__device__ __forceinline__ uint4 hop_pair4(
    int e_self, int q, int p, const int* __restrict__ adj_e,
    const int* __restrict__ adj_r, const uint* __restrict__ embB,
    const uint* __restrict__ relB, const uint* __restrict__ neibB,
    const float* __restrict__ Wa, float* __restrict__ alds) {
  uint4 us = ((const uint4*)(embB + (size_t)e_self * 64))[q];
  float s[8], wa[8], sw[8];
  unpack8(us, s);
  *(float4*)&wa[0] = ((const float4*)Wa)[q * 2];
  *(float4*)&wa[4] = ((const float4*)Wa)[q * 2 + 1];
#pragma unroll
  for (int d = 0; d < 8; d++) sw[d] = s[d] * wa[d];

  int4 ra = ((const int4*)(adj_r + (size_t)e_self * 8))[0];
  int4 rb = ((const int4*)(adj_r + (size_t)e_self * 8))[1];
  int rk[8] = {ra.x, ra.y, ra.z, ra.w, rb.x, rb.y, rb.z, rb.w};

  uint4 nbp[8];
  if (neibB == nullptr) {
    int4 ea = ((const int4*)(adj_e + (size_t)e_self * 8))[0];
    int4 eb = ((const int4*)(adj_e + (size_t)e_self * 8))[1];
    int e2[8] = {ea.x, ea.y, ea.z, ea.w, eb.x, eb.y, eb.z, eb.w};
#pragma unroll
    for (int k = 0; k < 8; k++)
      nbp[k] = ((const uint4*)(embB + (size_t)e2[k] * 64))[q];
  } else {
#pragma unroll
    for (int k = 0; k < 8; k++)
      nbp[k] = ((const uint4*)(neibB + ((size_t)p * 8 + k) * 64))[q];
  }

  float t[8];
#pragma unroll
  for (int k = 0; k < 8; k++) {
    uint4 ur = ((const uint4*)(relB + (size_t)rk[k] * 64))[q];
    float rr[8], nb[8];
    unpack8(ur, rr);
    unpack8(nbp[k], nb);
    float tt = 0.f;
#pragma unroll
    for (int d = 0; d < 8; d++) tt = fmaf(sw[d] * rr[d], nb[d], tt);
    t[k] = tt;
  }

  // multi-value halving butterfly within 16 lanes: 8 values -> 1 per lane
  bool b0 = (q & 1), b1 = (q & 2), b2 = (q & 4);
  float a4[4];
#pragma unroll
  for (int i = 0; i < 4; i++) {
    float send = b0 ? t[i] : t[4 + i];
    float recv = __shfl_xor(send, 1);
    a4[i] = (b0 ? t[4 + i] : t[i]) + recv;
  }
  float a2[2];
#pragma unroll
  for (int i = 0; i < 2; i++) {
    float send = b1 ? a4[i] : a4[2 + i];
    float recv = __shfl_xor(send, 2);
    a2[i] = (b1 ? a4[2 + i] : a4[i]) + recv;
  }
  float send1 = b2 ? a2[0] : a2[1];
  float recv1 = __shfl_xor(send1, 4);
  float c = (b2 ? a2[1] : a2[0]) + recv1;
  c += __shfl_xor(c, 8);  // att[k*], k* = (q&1)*4 + (q&2) + ((q&4)>>2)

  // softmax over 8 k-classes (|att|<=~0.04: no max-subtraction needed)
  float e = __expf(c);
  float den = e;
  den += __shfl_xor(den, 1);
  den += __shfl_xor(den, 2);
  den += __shfl_xor(den, 4);
  float alpha = e * __builtin_amdgcn_rcpf(den);

  // broadcast alphas via per-group LDS slot (wave-synchronous)
  int kstar = (q & 1) * 4 + (q & 2) + ((q & 4) >> 2);
  if (q < 8) alds[kstar] = alpha;
  asm volatile("s_waitcnt lgkmcnt(0)" ::: "memory");
  float a8[8];
  *(float4*)&a8[0] = ((const float4*)alds)[0];
  *(float4*)&a8[4] = ((const float4*)alds)[1];

  float x[8];
#pragma unroll
  for (int d = 0; d < 8; d++) x[d] = s[d];
#pragma unroll
  for (int k = 0; k < 8; k++) {
    float nb[8];
    unpack8(nbp[k], nb);
#pragma unroll
    for (int d = 0; d < 8; d++) x[d] = fmaf(a8[k], nb[d], x[d]);
  }
  uint4 o;
  o.x = packbf(x[0], x[1]);
  o.y = packbf(x[2], x[3]);
  o.z = packbf(x[4], x[5]);
  o.w = packbf(x[6], x[7]);
  return o;
}

// ---------------- fused hop0 + lin0: 16 pairs/block, single pair per group ----------------
// 6400 blocks x 256 threads. R15 PM: the 2-iteration loop serialized each
// wave's gather chains (regalloc couldn't overlap them at VGPR=92). One pair
// per group moves that parallelism to the wave scheduler / cross-block overlap.
__global__ __launch_bounds__(256) void hoplin_kernel(
    const int* __restrict__ h_iids, const int* __restrict__ adj_e,
    const int* __restrict__ adj_r, const uint* __restrict__ embB,
    const uint* __restrict__ relB, const float* __restrict__ Wa,
    const ushort* __restrict__ WtT, const float* __restrict__ bt,
    ushort* __restrict__ NEIB) {
  __shared__ ushort X0s[16 * 128];  // XOR-swizzled
  __shared__ float als[16][8];
  const int bx = blockIdx.x;
  const int wv = threadIdx.x >> 6, ln = threadIdx.x & 63;
  const int g = ln >> 4, q = ln & 15;
  const int lp = wv * 4 + g;  // local pair 0..15
  const int p = bx * 16 + lp;

  int b = p / (NB_S * NB_NB);
  int m = p % (NB_S * NB_NB);
  int h = h_iids[b * NB_S + (m >> 3)];
  int e_self = adj_e[h * NB_NB + (m & 7)];
  uint4 o = hop_pair4(e_self, q, p, adj_e, adj_r, embB, relB, nullptr, Wa,
                      als[lp]);
  {
    int byte = (lp * 256 + q * 16) ^ ((lp & 7) << 4);
    *(uint4*)((char*)X0s + byte) = o;
  }
  __syncthreads();

  // MFMA: NEIB[16 rows][128] = X0s @ WtT^T + bt; wave wv covers cols [32wv,32wv+32)
  const int lr = ln & 15, lg = ln >> 4;
  short8 afr[4];
#pragma unroll
  for (int kf = 0; kf < 4; kf++) {
    int byte = (lr * 256 + lg * 16 + kf * 64) ^ ((lr & 7) << 4);
    afr[kf] = *(const short8*)((const char*)X0s + byte);
  }
  f32x4 acc[2] = {};
#pragma unroll
  for (int nf = 0; nf < 2; nf++) {
    int n = (wv * 2 + nf) * 16 + lr;
    const ushort* bb = WtT + (size_t)n * 128 + lg * 8;
#pragma unroll
    for (int kf = 0; kf < 4; kf++) {
      short8 bv = *(const short8*)(bb + kf * 32);
      acc[nf] = __builtin_amdgcn_mfma_f32_16x16x32_bf16(afr[kf], bv, acc[nf],
                                                        0, 0, 0);
    }
  }
#pragma unroll
  for (int nf = 0; nf < 2; nf++) {
    int n = (wv * 2 + nf) * 16 + lr;
    float bv = bt[n];
#pragma unroll
    for (int r = 0; r < 4; r++) {
      int mg = bx * 16 + lg * 4 + r;
      NEIB[(size_t)mg * 128 + n] = f2bf(acc[nf][r] + bv);
    }
  }
}

// ---------------- fused hop1 + SEQ GEMM + GI GEMM ----------------
__global__ __launch_bounds__(256) void hopgi_kernel(
    const int* __restrict__ h_iids, const int* __restrict__ adj_e,
    const int* __restrict__ adj_r, const uint* __restrict__ embB,
    const uint* __restrict__ relB, const uint* __restrict__ neibB,
    const float* __restrict__ Wa, const ushort* __restrict__ WtT,
    const float* __restrict__ bt, const ushort* __restrict__ WihT,
    const float* __restrict__ GIBIAS, float* __restrict__ GI) {
  __shared__ ushort X1s[16 * 128];  // XOR-swizzled
  __shared__ ushort SEQs[16 * 128]; // XOR-swizzled
  __shared__ float als[16][8];
  const int wv = threadIdx.x >> 6, ln = threadIdx.x & 63;
  const int g = ln >> 4, q = ln & 15;
  const int lp = wv * 4 + g;  // local pair 0..15
  const int p = blockIdx.x * 16 + lp;

  int e_self = h_iids[p];
  uint4 o = hop_pair4(e_self, q, p, adj_e, adj_r, embB, relB, neibB, Wa, als[lp]);
  {
    int byte = (lp * 256 + q * 16) ^ ((lp & 7) << 4);
    *(uint4*)((char*)X1s + byte) = o;
  }
  __syncthreads();

  const int lr = ln & 15, lg = ln >> 4;
  // phase 2: SEQ = X1 @ WtT + bt; wave covers cols [wv*32, wv*32+32)
  {
    short8 afr[4];
#pragma unroll
    for (int kf = 0; kf < 4; kf++) {
      int byte = (lr * 256 + lg * 16 + kf * 64) ^ ((lr & 7) << 4);
      afr[kf] = *(const short8*)((const char*)X1s + byte);
    }
    f32x4 acc[2] = {};
#pragma unroll
    for (int nf = 0; nf < 2; nf++) {
      int n = (wv * 2 + nf) * 16 + lr;
      const ushort* bb = WtT + (size_t)n * 128 + lg * 8;
#pragma unroll
      for (int kf = 0; kf < 4; kf++) {
        short8 b = *(const short8*)(bb + kf * 32);
        acc[nf] = __builtin_amdgcn_mfma_f32_16x16x32_bf16(afr[kf], b, acc[nf],
                                                          0, 0, 0);
      }
    }
#pragma unroll
    for (int nf = 0; nf < 2; nf++) {
      int n = (wv * 2 + nf) * 16 + lr;
      float bv = bt[n];
#pragma unroll
      for (int r = 0; r < 4; r++) {
        int m = lg * 4 + r;
        int byte = (m * 256 + n * 2) ^ ((m & 7) << 4);
        *(ushort*)((char*)SEQs + byte) = f2bf(acc[nf][r] + bv);
      }
    }
  }
  __syncthreads();

  // phase 3: GI = SEQ @ WihT + GIBIAS; wave covers cols [wv*96, wv*96+96)
  {
    short8 sfr[4];
#pragma unroll
    for (int kf = 0; kf < 4; kf++) {
      int byte = (lr * 256 + lg * 16 + kf * 64) ^ ((lr & 7) << 4);
      sfr[kf] = *(const short8*)((const char*)SEQs + byte);
    }
#pragma unroll
    for (int i = 0; i < 6; i++) {
      int n = (wv * 6 + i) * 16 + lr;
      const ushort* bb = WihT + (size_t)n * 128 + lg * 8;
      f32x4 a2 = {};
#pragma unroll
      for (int kf = 0; kf < 4; kf++) {
        short8 b = *(const short8*)(bb + kf * 32);
        a2 = __builtin_amdgcn_mfma_f32_16x16x32_bf16(sfr[kf], b, a2, 0, 0, 0);
      }
      float bv = GIBIAS[n];
#pragma unroll
      for (int r = 0; r < 4; r++) {
        int m = lg * 4 + r;
        GI[(size_t)(blockIdx.x * 16 + m) * 384 + n] = a2[r] + bv;
      }
    }
  }
}

// ---------------- GRU: lane-local gates, depth-3 pipeline, exp2 prescaled ----------------
__global__ __launch_bounds__(512) void gru_mfma_kernel(
    const float* __restrict__ GI, const ushort* __restrict__ WhhT_bf,
    const float* __restrict__ bhh, ushort* __restrict__ OUTB) {
  const int b0 = blockIdx.x * 16;
  const int tid = threadIdx.x;
  const int w = tid >> 6, ln = tid & 63;
  const int lr = ln & 15, lg = ln >> 4;
  const int j = w * 16 + lr;

  __shared__ ushort hA[16 * 128];
  __shared__ ushort hB[16 * 128];

  short8 bfr[3][4];
#pragma unroll
  for (int g = 0; g < 3; g++) {
    const ushort* bb = WhhT_bf + (size_t)(g * 128 + j) * 128 + lg * 8;
#pragma unroll
    for (int kf = 0; kf < 4; kf++) bfr[g][kf] = *(const short8*)(bb + kf * 32);
  }
  const float bhn = C_N * bhh[256 + j];

  float h_reg[4] = {0.f, 0.f, 0.f, 0.f};

  {
    uint* hz = (uint*)hA;
#pragma unroll
    for (int i = tid; i < 1024; i += 512) hz[i] = 0;
  }
  __syncthreads();

  float girA[4][3], girB[4][3], girC[4][3], girD[4][3];
#pragma unroll
  for (int r = 0; r < 4; r++) {
    const float* g0 = GI + ((size_t)(b0 + lg * 4 + r) * NB_S + 0) * 384 + j;
    girA[r][0] = g0[0]; girA[r][1] = g0[128]; girA[r][2] = g0[256];
    const float* g1 = GI + ((size_t)(b0 + lg * 4 + r) * NB_S + 1) * 384 + j;
    girB[r][0] = g1[0]; girB[r][1] = g1[128]; girB[r][2] = g1[256];
    const float* g2 = GI + ((size_t)(b0 + lg * 4 + r) * NB_S + 2) * 384 + j;
    girC[r][0] = g2[0]; girC[r][1] = g2[128]; girC[r][2] = g2[256];
  }

  auto STEP = [&](int t, ushort* hRead, ushort* hWrite, float (&cur)[4][3],
                  float (&pre3)[4][3]) {
    if (t + 3 < NB_S) {
#pragma unroll
      for (int r = 0; r < 4; r++) {
        const float* g = GI + ((size_t)(b0 + lg * 4 + r) * NB_S + (t + 3)) * 384 + j;
        pre3[r][0] = g[0]; pre3[r][1] = g[128]; pre3[r][2] = g[256];
      }
    }
    __builtin_amdgcn_sched_barrier(0);
    short8 afr[4];
#pragma unroll
    for (int kf = 0; kf < 4; kf++) {
      int byte = (lr * 256 + kf * 64 + lg * 16) ^ ((lr & 7) << 4);
      afr[kf] = *(const short8*)((const char*)hRead + byte);
    }
    f32x4 acc[3] = {};
#pragma unroll
    for (int g = 0; g < 3; g++)
#pragma unroll
      for (int kf = 0; kf < 4; kf++)
        acc[g] = __builtin_amdgcn_mfma_f32_16x16x32_bf16(afr[kf], bfr[g][kf],
                                                         acc[g], 0, 0, 0);
#pragma unroll
    for (int r = 0; r < 4; r++) {
      int b = lg * 4 + r;
      float rg = __builtin_amdgcn_rcpf(
          1.f + __builtin_amdgcn_exp2f(cur[r][0] + acc[0][r]));
      float ze = __builtin_amdgcn_exp2f(cur[r][1] + acc[1][r]);
      float xp = cur[r][2] + rg * (bhn + acc[2][r]);
      float e2 = __builtin_amdgcn_exp2f(xp);
      float n = 1.f - 2.f * __builtin_amdgcn_rcpf(e2 + 1.f);
      float h2 = n + (h_reg[r] - n) * __builtin_amdgcn_rcpf(1.f + ze);
      h_reg[r] = h2;
      ushort hb = f2bf(h2);
      OUTB[((size_t)(b0 + b) * NB_S + t) * 128 + j] = hb;
      int byte = (b * 256 + j * 2) ^ ((b & 7) << 4);
      *(ushort*)((char*)hWrite + byte) = hb;
    }
    asm volatile("s_waitcnt lgkmcnt(0)" ::: "memory");
    __builtin_amdgcn_s_barrier();
  };

  for (int g4 = 0; g4 < 12; g4++) {
    int t = g4 * 4;
    STEP(t + 0, hA, hB, girA, girD);
    STEP(t + 1, hB, hA, girB, girA);
    STEP(t + 2, hA, hB, girC, girB);
    STEP(t + 3, hB, hA, girD, girC);
  }
  STEP(48, hA, hB, girA, girD);
  STEP(49, hB, hA, girB, girA);
}

// ---------------- fused pooling (reads bf16 OUTB) ----------------
__global__ __launch_bounds__(256) void pool_kernel(
    const int* __restrict__ h_iids, const ushort* __restrict__ OUTB,
    const float* __restrict__ W1, const float* __restrict__ b1,
    const ushort* __restrict__ W2T, const float* __restrict__ b2,
    const float* __restrict__ W3, const float* __restrict__ Wtr,
    const float* __restrict__ btr, ushort* __restrict__ GHT_bf) {
  const int b = blockIdx.x, tid = threadIdx.x;
  __shared__ float lh[128];
  __shared__ float q1[128];
  __shared__ float al[64];
  __shared__ float cat[256];

  if (tid < 128) {
    int cnt = 0;
    for (int s = 0; s < NB_S; s++) cnt += (h_iids[b * NB_S + s] != 0);
    int li = min(max(cnt - 1, 0), NB_S - 1);
    lh[tid] = bf2f(OUTB[((size_t)b * NB_S + li) * 128 + tid]);
  }
  __syncthreads();
  if (tid < 128) {
    float acc = b1[tid];
    for (int d = 0; d < 128; d++) acc += lh[d] * W1[(size_t)d * 128 + tid];
    q1[tid] = acc;
  }
  __syncthreads();

  {
    const int wv = tid >> 6, ln = tid & 63, lr = ln & 15, lg = ln >> 4;
    const int s0 = wv * 16;
    short8 zz = {0, 0, 0, 0, 0, 0, 0, 0};
    short8 afr[4];
    int srow = s0 + lr;
#pragma unroll
    for (int kf = 0; kf < 4; kf++)
      afr[kf] = (srow < NB_S)
                    ? *(const short8*)(OUTB + ((size_t)b * NB_S + srow) * 128 +
                                       lg * 8 + kf * 32)
                    : zz;
    float part[4] = {0.f, 0.f, 0.f, 0.f};
#pragma unroll
    for (int nf = 0; nf < 8; nf++) {
      const ushort* bb = W2T + (size_t)(nf * 16 + lr) * 128 + lg * 8;
      f32x4 acc = {};
#pragma unroll
      for (int kf = 0; kf < 4; kf++) {
        short8 bv = *(const short8*)(bb + kf * 32);
        acc = __builtin_amdgcn_mfma_f32_16x16x32_bf16(afr[kf], bv, acc, 0, 0, 0);
      }
      int c = nf * 16 + lr;
      float qc = q1[c] + b2[c];
      float w3 = W3[c];
#pragma unroll
      for (int r = 0; r < 4; r++)
        part[r] += w3 / (1.f + __expf(-(qc + acc[r])));
    }
#pragma unroll
    for (int r = 0; r < 4; r++) {
#pragma unroll
      for (int off = 1; off < 16; off <<= 1) part[r] += __shfl_xor(part[r], off);
      int s = s0 + lg * 4 + r;
      if (lr == 0 && s < NB_S) al[s] = part[r];
    }
  }
  __syncthreads();

  if (tid < 128) {
    float g = 0.f;
    for (int s = 0; s < NB_S; s++)
      g += al[s] * bf2f(OUTB[((size_t)b * NB_S + s) * 128 + tid]);
    cat[tid] = lh[tid];
    cat[128 + tid] = g;
  }
  __syncthreads();
  if (tid < 128) {
    float acc = btr[tid];
    for (int dd = 0; dd < 256; dd++) acc += cat[dd] * Wtr[(size_t)dd * 128 + tid];
    GHT_bf[b * 128 + tid] = f2bf(acc);
  }
}

// ---------------- logits = relu(GHT_bf @ EMB_BF^T) via MFMA ----------------
__global__ __launch_bounds__(256) void logits_mfma_kernel(
    const ushort* __restrict__ GHT_bf, const ushort* __restrict__ embB,
    float* __restrict__ out) {
  int wave = (int)(blockIdx.x * 4 + (threadIdx.x >> 6));
  int ln = threadIdx.x & 63;
  int n0 = __builtin_amdgcn_readfirstlane(wave) * 32;
  if (n0 >= NB_NITEMS) return;
  int lr = ln & 15, lg = ln >> 4;

  short8 bfr[2][4];
#pragma unroll
  for (int nf = 0; nf < 2; nf++) {
    const ushort* base = embB + (size_t)(n0 + nf * 16 + lr) * 128 + lg * 8;
#pragma unroll
    for (int kf = 0; kf < 4; kf++) bfr[nf][kf] = *(const short8*)(base + kf * 32);
  }

  f32x4 acc[16][2] = {};
#pragma unroll
  for (int mg = 0; mg < 4; mg++) {
    short8 afr[4][4];
#pragma unroll
    for (int mf = 0; mf < 4; mf++) {
      const ushort* ab = GHT_bf + (size_t)((mg * 4 + mf) * 16 + lr) * 128 + lg * 8;
#pragma unroll
      for (int kf = 0; kf < 4; kf++) afr[mf][kf] = *(const short8*)(ab + kf * 32);
    }
#pragma unroll
    for (int mf = 0; mf < 4; mf++)
#pragma unroll
      for (int nf = 0; nf < 2; nf++)
#pragma unroll
        for (int kf = 0; kf < 4; kf++)
          acc[mg * 4 + mf][nf] = __builtin_amdgcn_mfma_f32_16x16x32_bf16(
              afr[mf][kf], bfr[nf][kf], acc[mg * 4 + mf][nf], 0, 0, 0);
  }

#pragma unroll
  for (int mf = 0; mf < 16; mf++)
#pragma unroll
    for (int nf = 0; nf < 2; nf++) {
      int n = n0 + nf * 16 + lr;
#pragma unroll
      for (int r = 0; r < 4; r++) {
        int m = mf * 16 + lg * 4 + r;
        out[(size_t)m * NB_NITEMS + n] = fmaxf(acc[mf][nf][r], 0.f);
      }
    }
}

extern "C" void kernel_launch(void* const* d_in, const int* in_sizes, int n_in,
                              void* d_out, int out_size, void* d_ws, size_t ws_size,
                              hipStream_t stream) {
  const int* h_iids = (const int*)d_in[0];
  const int* adj_e = (const int*)d_in[2];
  const int* adj_r = (const int*)d_in[3];
  const float* item_emb = (const float*)d_in[4];
  const float* rel_emb = (const float*)d_in[5];
  const float* Wa = (const float*)d_in[6];
  const float* Wt = (const float*)d_in[8];
  const float* bt = (const float*)d_in[9];
  const float* Wih = (const float*)d_in[10];
  const float* Whh = (const float*)d_in[11];
  const float* bih = (const float*)d_in[12];
  const float* bhh = (const float*)d_in[13];
  const float* W1 = (const float*)d_in[14];
  const float* b1 = (const float*)d_in[15];
  const float* W2 = (const float*)d_in[16];
  const float* b2 = (const float*)d_in[17];
  const float* W3 = (const float*)d_in[18];
  const float* Wtr = (const float*)d_in[19];
  const float* btr = (const float*)d_in[20];
  float* out = (float*)d_out;

  // ws layout (bytes), all 16B-aligned. ~76 MB total.
  char* w = (char*)d_ws;
  uint* EMB_BF = (uint*)w;                    w += 25600000;  // 100000x128 bf16
  uint* REL_BF = (uint*)w;                    w += 51200;     // 200x128 bf16
  ushort* WtT_bf = (ushort*)w;                w += 32768;     // [128][128]
  ushort* WihT_bf = (ushort*)w;               w += 98304;     // [384][128] scaled
  ushort* WhhT_bf = (ushort*)w;               w += 98304;     // [384][128] scaled
  ushort* W2T_bf = (ushort*)w;                w += 32768;     // [128][128]
  float* GIBIAS = (float*)w;                  w += 2048;      // 384 floats
  uint* NEIB_bf = (uint*)w;                   w += 26214400;  // 102400x128 bf16
  float* GI = (float*)w;                      w += 19660800;  // 12800x384 fp32
  ushort* OUTB = (ushort*)w;                  w += 3276800;   // 12800x128 bf16
  ushort* GHT_bf = (ushort*)w;                w += 65536;

  // ---- fused prep (1 launch) ----
  prep_kernel<<<6777, 256, 0, stream>>>(item_emb, rel_emb, Wt, Wih, Whh, W2,
                                        bih, bhh, EMB_BF, REL_BF, WtT_bf,
                                        WihT_bf, WhhT_bf, W2T_bf, GIBIAS);

  // ---- KG hops (hop0+Wt fused; hop1+Wt+Wih fused) ----
  hoplin_kernel<<<6400, 256, 0, stream>>>(h_iids, adj_e, adj_r, EMB_BF, REL_BF,
                                          Wa, WtT_bf, bt, (ushort*)NEIB_bf);
  hopgi_kernel<<<800, 256, 0, stream>>>(h_iids, adj_e, adj_r, EMB_BF, REL_BF,
                                        NEIB_bf, Wa, WtT_bf, bt, WihT_bf,
                                        GIBIAS, GI);

  // ---- GRU + fused pooling ----
  gru_mfma_kernel<<<16, 512, 0, stream>>>(GI, WhhT_bf, bhh, OUTB);
  pool_kernel<<<256, 256, 0, stream>>>(h_iids, OUTB, W1, b1, W2T_bf, b2, W3,
                                       Wtr, btr, GHT_bf);

  // ---- logits ----
  logits_mfma_kernel<<<782, 256, 0, stream>>>(GHT_bf, (const ushort*)EMB_BF, out);
}

// Round 17
// 190.877 us; speedup vs baseline: 1.3918x; 1.1205x over previous
//
#include <hip/hip_runtime.h>
#include <hip/hip_bf16.h>
#include <math.h>

#define NB_B 256
#define NB_S 50
#define NB_NB 8
#define NB_D 128
#define NB_NITEMS 100000

#define C_RZ (-1.442695041f)   // -log2(e): sigmoid arg prescale
#define C_N (2.885390082f)     // 2*log2(e): tanh arg prescale

typedef __attribute__((ext_vector_type(8))) short short8;   // 8 x bf16 (4 VGPR)
typedef __attribute__((ext_vector_type(4))) float f32x4;    // MFMA acc
typedef unsigned int uint;
typedef unsigned short ushort;

// fp32 -> bf16 round-to-nearest-even
__device__ __forceinline__ ushort f2bf(float f) {
  union { float f; uint u; } v;
  v.f = f;
  return (ushort)((v.u + 0x7fffu + ((v.u >> 16) & 1u)) >> 16);
}
__device__ __forceinline__ uint packbf(float a, float b) {
  return (uint)f2bf(a) | ((uint)f2bf(b) << 16);
}
__device__ __forceinline__ float bflo(uint u) {
  union { uint u; float f; } v; v.u = u << 16; return v.f;
}
__device__ __forceinline__ float bfhi(uint u) {
  union { uint u; float f; } v; v.u = u & 0xffff0000u; return v.f;
}
__device__ __forceinline__ float bf2f(ushort u) {
  union { uint u; float f; } v; v.u = (uint)u << 16; return v.f;
}
__device__ __forceinline__ void unpack8(uint4 u, float* f) {
  f[0] = bflo(u.x); f[1] = bfhi(u.x);
  f[2] = bflo(u.y); f[3] = bfhi(u.y);
  f[4] = bflo(u.z); f[5] = bfhi(u.z);
  f[6] = bflo(u.w); f[7] = bfhi(u.w);
}

// ---------------- fused prep: casts + scaled transposes + GI bias + E0 ids ----------------
__device__ __forceinline__ void castf_body(const float* __restrict__ src,
                                           uint* __restrict__ dst, int i, int n8) {
  if (i >= n8) return;
  float4 a = ((const float4*)src)[2 * i];
  float4 b = ((const float4*)src)[2 * i + 1];
  uint4 o;
  o.x = packbf(a.x, a.y);
  o.y = packbf(a.z, a.w);
  o.z = packbf(b.x, b.y);
  o.w = packbf(b.z, b.w);
  ((uint4*)dst)[i] = o;
}
template <int CO, bool SCALED>
__device__ __forceinline__ void castT_body(const float* __restrict__ W,
                                           ushort* __restrict__ WT, int idx) {
  if (idx >= 128 * CO) return;
  int n = idx >> 7, k = idx & 127;
  float v = W[(size_t)k * CO + n];
  if (SCALED) v *= (n < 256 ? C_RZ : C_N);
  WT[idx] = f2bf(v);
}
__global__ __launch_bounds__(256) void prep_kernel(
    const float* __restrict__ item_emb, const float* __restrict__ rel_emb,
    const float* __restrict__ Wt, const float* __restrict__ Wih,
    const float* __restrict__ Whh, const float* __restrict__ W2,
    const float* __restrict__ bih, const float* __restrict__ bhh,
    const int* __restrict__ h_iids, const int* __restrict__ adj_e,
    uint* __restrict__ EMB_BF, uint* __restrict__ REL_BF,
    ushort* __restrict__ WtT, ushort* __restrict__ WihT,
    ushort* __restrict__ WhhT, ushort* __restrict__ W2T,
    float* __restrict__ GIBIAS, int* __restrict__ E0) {
  int bx = blockIdx.x, tid = threadIdx.x;
  if (bx < 6250) {
    castf_body(item_emb, EMB_BF, bx * 256 + tid, 1600000);
  } else if (bx < 6263) {
    castf_body(rel_emb, REL_BF, (bx - 6250) * 256 + tid, 3200);
  } else if (bx < 6327) {
    castT_body<128, false>(Wt, WtT, (bx - 6263) * 256 + tid);
  } else if (bx < 6519) {
    castT_body<384, true>(Wih, WihT, (bx - 6327) * 256 + tid);
  } else if (bx < 6711) {
    castT_body<384, true>(Whh, WhhT, (bx - 6519) * 256 + tid);
  } else if (bx < 6775) {
    castT_body<128, false>(W2, W2T, (bx - 6711) * 256 + tid);
  } else if (bx < 6776) {
    int idx = tid;
    if (idx < 256) {
      GIBIAS[idx] = C_RZ * (bih[idx] + bhh[idx]);
    }
    // idx 256..383 handled in next block range (see below)
  } else if (bx < 6777) {
    int idx = 256 + tid;
    if (idx < 384) GIBIAS[idx] = C_N * bih[idx];
  } else {
    int p = (bx - 6777) * 256 + tid;
    if (p < NB_B * NB_S * NB_NB) {
      int b = p / (NB_S * NB_NB);
      int m = p % (NB_S * NB_NB);
      int h = h_iids[b * NB_S + (m >> 3)];
      E0[p] = adj_e[h * NB_NB + (m & 7)];
    }
  }
}

// ---------------- hop pair: 16-lane group, 8 dims/lane, multi-value reduce ----------------
__device__ __forceinline__ uint4 hop_pair4(
    int e_self, int q, int p, const int* __restrict__ adj_e,
    const int* __restrict__ adj_r, const uint* __restrict__ embB,
    const uint* __restrict__ relB, const uint* __restrict__ neibB,
    const float* __restrict__ Wa, float* __restrict__ alds) {
  uint4 us = ((const uint4*)(embB + (size_t)e_self * 64))[q];
  float s[8], wa[8], sw[8];
  unpack8(us, s);
  *(float4*)&wa[0] = ((const float4*)Wa)[q * 2];
  *(float4*)&wa[4] = ((const float4*)Wa)[q * 2 + 1];
#pragma unroll
  for (int d = 0; d < 8; d++) sw[d] = s[d] * wa[d];

  int4 ra = ((const int4*)(adj_r + (size_t)e_self * 8))[0];
  int4 rb = ((const int4*)(adj_r + (size_t)e_self * 8))[1];
  int rk[8] = {ra.x, ra.y, ra.z, ra.w, rb.x, rb.y, rb.z, rb.w};

  uint4 nbp[8];
  if (neibB == nullptr) {
    int4 ea = ((const int4*)(adj_e + (size_t)e_self * 8))[0];
    int4 eb = ((const int4*)(adj_e + (size_t)e_self * 8))[1];
    int e2[8] = {ea.x, ea.y, ea.z, ea.w, eb.x, eb.y, eb.z, eb.w};
#pragma unroll
    for (int k = 0; k < 8; k++)
      nbp[k] = ((const uint4*)(embB + (size_t)e2[k] * 64))[q];
  } else {
#pragma unroll
    for (int k = 0; k < 8; k++)
      nbp[k] = ((const uint4*)(neibB + ((size_t)p * 8 + k) * 64))[q];
  }

  float t[8];
#pragma unroll
  for (int k = 0; k < 8; k++) {
    uint4 ur = ((const uint4*)(relB + (size_t)rk[k] * 64))[q];
    float rr[8], nb[8];
    unpack8(ur, rr);
    unpack8(nbp[k], nb);
    float tt = 0.f;
#pragma unroll
    for (int d = 0; d < 8; d++) tt = fmaf(sw[d] * rr[d], nb[d], tt);
    t[k] = tt;
  }

  // multi-value halving butterfly within 16 lanes: 8 values -> 1 per lane
  bool b0 = (q & 1), b1 = (q & 2), b2 = (q & 4);
  float a4[4];
#pragma unroll
  for (int i = 0; i < 4; i++) {
    float send = b0 ? t[i] : t[4 + i];
    float recv = __shfl_xor(send, 1);
    a4[i] = (b0 ? t[4 + i] : t[i]) + recv;
  }
  float a2[2];
#pragma unroll
  for (int i = 0; i < 2; i++) {
    float send = b1 ? a4[i] : a4[2 + i];
    float recv = __shfl_xor(send, 2);
    a2[i] = (b1 ? a4[2 + i] : a4[i]) + recv;
  }
  float send1 = b2 ? a2[0] : a2[1];
  float recv1 = __shfl_xor(send1, 4);
  float c = (b2 ? a2[1] : a2[0]) + recv1;
  c += __shfl_xor(c, 8);  // att[k*], k* = (q&1)*4 + (q&2) + ((q&4)>>2)

  // softmax over 8 k-classes (|att|<=~0.04: no max-subtraction needed)
  float e = __expf(c);
  float den = e;
  den += __shfl_xor(den, 1);
  den += __shfl_xor(den, 2);
  den += __shfl_xor(den, 4);
  float alpha = e * __builtin_amdgcn_rcpf(den);

  // broadcast alphas via per-group LDS slot (wave-synchronous)
  int kstar = (q & 1) * 4 + (q & 2) + ((q & 4) >> 2);
  if (q < 8) alds[kstar] = alpha;
  asm volatile("s_waitcnt lgkmcnt(0)" ::: "memory");
  float a8[8];
  *(float4*)&a8[0] = ((const float4*)alds)[0];
  *(float4*)&a8[4] = ((const float4*)alds)[1];

  float x[8];
#pragma unroll
  for (int d = 0; d < 8; d++) x[d] = s[d];
#pragma unroll
  for (int k = 0; k < 8; k++) {
    float nb[8];
    unpack8(nbp[k], nb);
#pragma unroll
    for (int d = 0; d < 8; d++) x[d] = fmaf(a8[k], nb[d], x[d]);
  }
  uint4 o;
  o.x = packbf(x[0], x[1]);
  o.y = packbf(x[2], x[3]);
  o.z = packbf(x[4], x[5]);
  o.w = packbf(x[6], x[7]);
  return o;
}

// ---------------- fused hop0 + lin0: 16 pairs/block, E0-precomputed ids ----------------
__global__ __launch_bounds__(256) void hoplin_kernel(
    const int* __restrict__ E0, const int* __restrict__ adj_e,
    const int* __restrict__ adj_r, const uint* __restrict__ embB,
    const uint* __restrict__ relB, const float* __restrict__ Wa,
    const ushort* __restrict__ WtT, const float* __restrict__ bt,
    ushort* __restrict__ NEIB) {
  __shared__ ushort X0s[16 * 128];  // XOR-swizzled
  __shared__ float als[16][8];
  const int bx = blockIdx.x;
  const int wv = threadIdx.x >> 6, ln = threadIdx.x & 63;
  const int g = ln >> 4, q = ln & 15;
  const int lp = wv * 4 + g;  // local pair 0..15
  const int p = bx * 16 + lp;

  int e_self = E0[p];
  uint4 o = hop_pair4(e_self, q, p, adj_e, adj_r, embB, relB, nullptr, Wa,
                      als[lp]);
  {
    int byte = (lp * 256 + q * 16) ^ ((lp & 7) << 4);
    *(uint4*)((char*)X0s + byte) = o;
  }
  __syncthreads();

  // MFMA: NEIB[16 rows][128] = X0s @ WtT^T + bt; wave wv covers cols [32wv,32wv+32)
  const int lr = ln & 15, lg = ln >> 4;
  short8 afr[4];
#pragma unroll
  for (int kf = 0; kf < 4; kf++) {
    int byte = (lr * 256 + lg * 16 + kf * 64) ^ ((lr & 7) << 4);
    afr[kf] = *(const short8*)((const char*)X0s + byte);
  }
  f32x4 acc[2] = {};
#pragma unroll
  for (int nf = 0; nf < 2; nf++) {
    int n = (wv * 2 + nf) * 16 + lr;
    const ushort* bb = WtT + (size_t)n * 128 + lg * 8;
#pragma unroll
    for (int kf = 0; kf < 4; kf++) {
      short8 bv = *(const short8*)(bb + kf * 32);
      acc[nf] = __builtin_amdgcn_mfma_f32_16x16x32_bf16(afr[kf], bv, acc[nf],
                                                        0, 0, 0);
    }
  }
#pragma unroll
  for (int nf = 0; nf < 2; nf++) {
    int n = (wv * 2 + nf) * 16 + lr;
    float bv = bt[n];
#pragma unroll
    for (int r = 0; r < 4; r++) {
      int mg = bx * 16 + lg * 4 + r;
      NEIB[(size_t)mg * 128 + n] = f2bf(acc[nf][r] + bv);
    }
  }
}

// ---------------- fused hop1 + SEQ GEMM + GI GEMM ----------------
__global__ __launch_bounds__(256) void hopgi_kernel(
    const int* __restrict__ h_iids, const int* __restrict__ adj_e,
    const int* __restrict__ adj_r, const uint* __restrict__ embB,
    const uint* __restrict__ relB, const uint* __restrict__ neibB,
    const float* __restrict__ Wa, const ushort* __restrict__ WtT,
    const float* __restrict__ bt, const ushort* __restrict__ WihT,
    const float* __restrict__ GIBIAS, float* __restrict__ GI) {
  __shared__ ushort X1s[16 * 128];  // XOR-swizzled
  __shared__ ushort SEQs[16 * 128]; // XOR-swizzled
  __shared__ float als[16][8];
  const int wv = threadIdx.x >> 6, ln = threadIdx.x & 63;
  const int g = ln >> 4, q = ln & 15;
  const int lp = wv * 4 + g;  // local pair 0..15
  const int p = blockIdx.x * 16 + lp;

  int e_self = h_iids[p];
  uint4 o = hop_pair4(e_self, q, p, adj_e, adj_r, embB, relB, neibB, Wa, als[lp]);
  {
    int byte = (lp * 256 + q * 16) ^ ((lp & 7) << 4);
    *(uint4*)((char*)X1s + byte) = o;
  }
  __syncthreads();

  const int lr = ln & 15, lg = ln >> 4;
  // phase 2: SEQ = X1 @ WtT + bt; wave covers cols [wv*32, wv*32+32)
  {
    short8 afr[4];
#pragma unroll
    for (int kf = 0; kf < 4; kf++) {
      int byte = (lr * 256 + lg * 16 + kf * 64) ^ ((lr & 7) << 4);
      afr[kf] = *(const short8*)((const char*)X1s + byte);
    }
    f32x4 acc[2] = {};
#pragma unroll
    for (int nf = 0; nf < 2; nf++) {
      int n = (wv * 2 + nf) * 16 + lr;
      const ushort* bb = WtT + (size_t)n * 128 + lg * 8;
#pragma unroll
      for (int kf = 0; kf < 4; kf++) {
        short8 b = *(const short8*)(bb + kf * 32);
        acc[nf] = __builtin_amdgcn_mfma_f32_16x16x32_bf16(afr[kf], b, acc[nf],
                                                          0, 0, 0);
      }
    }
#pragma unroll
    for (int nf = 0; nf < 2; nf++) {
      int n = (wv * 2 + nf) * 16 + lr;
      float bv = bt[n];
#pragma unroll
      for (int r = 0; r < 4; r++) {
        int m = lg * 4 + r;
        int byte = (m * 256 + n * 2) ^ ((m & 7) << 4);
        *(ushort*)((char*)SEQs + byte) = f2bf(acc[nf][r] + bv);
      }
    }
  }
  __syncthreads();

  // phase 3: GI = SEQ @ WihT + GIBIAS; wave covers cols [wv*96, wv*96+96)
  {
    short8 sfr[4];
#pragma unroll
    for (int kf = 0; kf < 4; kf++) {
      int byte = (lr * 256 + lg * 16 + kf * 64) ^ ((lr & 7) << 4);
      sfr[kf] = *(const short8*)((const char*)SEQs + byte);
    }
#pragma unroll
    for (int i = 0; i < 6; i++) {
      int n = (wv * 6 + i) * 16 + lr;
      const ushort* bb = WihT + (size_t)n * 128 + lg * 8;
      f32x4 a2 = {};
#pragma unroll
      for (int kf = 0; kf < 4; kf++) {
        short8 b = *(const short8*)(bb + kf * 32);
        a2 = __builtin_amdgcn_mfma_f32_16x16x32_bf16(sfr[kf], b, a2, 0, 0, 0);
      }
      float bv = GIBIAS[n];
#pragma unroll
      for (int r = 0; r < 4; r++) {
        int m = lg * 4 + r;
        GI[(size_t)(blockIdx.x * 16 + m) * 384 + n] = a2[r] + bv;
      }
    }
  }
}

// ---------------- GRU: lane-local gates, depth-3 pipeline, exp2 prescaled ----------------
__global__ __launch_bounds__(512) void gru_mfma_kernel(
    const float* __restrict__ GI, const ushort* __restrict__ WhhT_bf,
    const float* __restrict__ bhh, ushort* __restrict__ OUTB) {
  const int b0 = blockIdx.x * 16;
  const int tid = threadIdx.x;
  const int w = tid >> 6, ln = tid & 63;
  const int lr = ln & 15, lg = ln >> 4;
  const int j = w * 16 + lr;

  __shared__ ushort hA[16 * 128];
  __shared__ ushort hB[16 * 128];

  short8 bfr[3][4];
#pragma unroll
  for (int g = 0; g < 3; g++) {
    const ushort* bb = WhhT_bf + (size_t)(g * 128 + j) * 128 + lg * 8;
#pragma unroll
    for (int kf = 0; kf < 4; kf++) bfr[g][kf] = *(const short8*)(bb + kf * 32);
  }
  const float bhn = C_N * bhh[256 + j];

  float h_reg[4] = {0.f, 0.f, 0.f, 0.f};

  {
    uint* hz = (uint*)hA;
#pragma unroll
    for (int i = tid; i < 1024; i += 512) hz[i] = 0;
  }
  __syncthreads();

  float girA[4][3], girB[4][3], girC[4][3], girD[4][3];
#pragma unroll
  for (int r = 0; r < 4; r++) {
    const float* g0 = GI + ((size_t)(b0 + lg * 4 + r) * NB_S + 0) * 384 + j;
    girA[r][0] = g0[0]; girA[r][1] = g0[128]; girA[r][2] = g0[256];
    const float* g1 = GI + ((size_t)(b0 + lg * 4 + r) * NB_S + 1) * 384 + j;
    girB[r][0] = g1[0]; girB[r][1] = g1[128]; girB[r][2] = g1[256];
    const float* g2 = GI + ((size_t)(b0 + lg * 4 + r) * NB_S + 2) * 384 + j;
    girC[r][0] = g2[0]; girC[r][1] = g2[128]; girC[r][2] = g2[256];
  }

  auto STEP = [&](int t, ushort* hRead, ushort* hWrite, float (&cur)[4][3],
                  float (&pre3)[4][3]) {
    if (t + 3 < NB_S) {
#pragma unroll
      for (int r = 0; r < 4; r++) {
        const float* g = GI + ((size_t)(b0 + lg * 4 + r) * NB_S + (t + 3)) * 384 + j;
        pre3[r][0] = g[0]; pre3[r][1] = g[128]; pre3[r][2] = g[256];
      }
    }
    __builtin_amdgcn_sched_barrier(0);
    short8 afr[4];
#pragma unroll
    for (int kf = 0; kf < 4; kf++) {
      int byte = (lr * 256 + kf * 64 + lg * 16) ^ ((lr & 7) << 4);
      afr[kf] = *(const short8*)((const char*)hRead + byte);
    }
    f32x4 acc[3] = {};
#pragma unroll
    for (int g = 0; g < 3; g++)
#pragma unroll
      for (int kf = 0; kf < 4; kf++)
        acc[g] = __builtin_amdgcn_mfma_f32_16x16x32_bf16(afr[kf], bfr[g][kf],
                                                         acc[g], 0, 0, 0);
#pragma unroll
    for (int r = 0; r < 4; r++) {
      int b = lg * 4 + r;
      float rg = __builtin_amdgcn_rcpf(
          1.f + __builtin_amdgcn_exp2f(cur[r][0] + acc[0][r]));
      float ze = __builtin_amdgcn_exp2f(cur[r][1] + acc[1][r]);
      float xp = cur[r][2] + rg * (bhn + acc[2][r]);
      float e2 = __builtin_amdgcn_exp2f(xp);
      float n = 1.f - 2.f * __builtin_amdgcn_rcpf(e2 + 1.f);
      float h2 = n + (h_reg[r] - n) * __builtin_amdgcn_rcpf(1.f + ze);
      h_reg[r] = h2;
      ushort hb = f2bf(h2);
      OUTB[((size_t)(b0 + b) * NB_S + t) * 128 + j] = hb;
      int byte = (b * 256 + j * 2) ^ ((b & 7) << 4);
      *(ushort*)((char*)hWrite + byte) = hb;
    }
    asm volatile("s_waitcnt lgkmcnt(0)" ::: "memory");
    __builtin_amdgcn_s_barrier();
  };

  for (int g4 = 0; g4 < 12; g4++) {
    int t = g4 * 4;
    STEP(t + 0, hA, hB, girA, girD);
    STEP(t + 1, hB, hA, girB, girA);
    STEP(t + 2, hA, hB, girC, girB);
    STEP(t + 3, hB, hA, girD, girC);
  }
  STEP(48, hA, hB, girA, girD);
  STEP(49, hB, hA, girB, girA);
}

// ---------------- fused pooling (reads bf16 OUTB) ----------------
__global__ __launch_bounds__(256) void pool_kernel(
    const int* __restrict__ h_iids, const ushort* __restrict__ OUTB,
    const float* __restrict__ W1, const float* __restrict__ b1,
    const ushort* __restrict__ W2T, const float* __restrict__ b2,
    const float* __restrict__ W3, const float* __restrict__ Wtr,
    const float* __restrict__ btr, ushort* __restrict__ GHT_bf) {
  const int b = blockIdx.x, tid = threadIdx.x;
  __shared__ float lh[128];
  __shared__ float q1[128];
  __shared__ float al[64];
  __shared__ float cat[256];

  if (tid < 128) {
    int cnt = 0;
    for (int s = 0; s < NB_S; s++) cnt += (h_iids[b * NB_S + s] != 0);
    int li = min(max(cnt - 1, 0), NB_S - 1);
    lh[tid] = bf2f(OUTB[((size_t)b * NB_S + li) * 128 + tid]);
  }
  __syncthreads();
  if (tid < 128) {
    float acc = b1[tid];
    for (int d = 0; d < 128; d++) acc += lh[d] * W1[(size_t)d * 128 + tid];
    q1[tid] = acc;
  }
  __syncthreads();

  {
    const int wv = tid >> 6, ln = tid & 63, lr = ln & 15, lg = ln >> 4;
    const int s0 = wv * 16;
    short8 zz = {0, 0, 0, 0, 0, 0, 0, 0};
    short8 afr[4];
    int srow = s0 + lr;
#pragma unroll
    for (int kf = 0; kf < 4; kf++)
      afr[kf] = (srow < NB_S)
                    ? *(const short8*)(OUTB + ((size_t)b * NB_S + srow) * 128 +
                                       lg * 8 + kf * 32)
                    : zz;
    float part[4] = {0.f, 0.f, 0.f, 0.f};
#pragma unroll
    for (int nf = 0; nf < 8; nf++) {
      const ushort* bb = W2T + (size_t)(nf * 16 + lr) * 128 + lg * 8;
      f32x4 acc = {};
#pragma unroll
      for (int kf = 0; kf < 4; kf++) {
        short8 bv = *(const short8*)(bb + kf * 32);
        acc = __builtin_amdgcn_mfma_f32_16x16x32_bf16(afr[kf], bv, acc, 0, 0, 0);
      }
      int c = nf * 16 + lr;
      float qc = q1[c] + b2[c];
      float w3 = W3[c];
#pragma unroll
      for (int r = 0; r < 4; r++)
        part[r] += w3 / (1.f + __expf(-(qc + acc[r])));
    }
#pragma unroll
    for (int r = 0; r < 4; r++) {
#pragma unroll
      for (int off = 1; off < 16; off <<= 1) part[r] += __shfl_xor(part[r], off);
      int s = s0 + lg * 4 + r;
      if (lr == 0 && s < NB_S) al[s] = part[r];
    }
  }
  __syncthreads();

  if (tid < 128) {
    float g = 0.f;
    for (int s = 0; s < NB_S; s++)
      g += al[s] * bf2f(OUTB[((size_t)b * NB_S + s) * 128 + tid]);
    cat[tid] = lh[tid];
    cat[128 + tid] = g;
  }
  __syncthreads();
  if (tid < 128) {
    float acc = btr[tid];
    for (int dd = 0; dd < 256; dd++) acc += cat[dd] * Wtr[(size_t)dd * 128 + tid];
    GHT_bf[b * 128 + tid] = f2bf(acc);
  }
}

// ---------------- logits = relu(GHT_bf @ EMB_BF^T) via MFMA ----------------
// 782 blocks x 256 threads; wave wv covers m in [wv*64, wv*64+64), n in
// [n0, n0+128). Per (m-row, wave) the 8 nf stores form a 512B contiguous run
// (vs 128B in the old acc[16][2] tiling) -> better DRAM burst locality.
__global__ __launch_bounds__(256) void logits_mfma_kernel(
    const ushort* __restrict__ GHT_bf, const ushort* __restrict__ embB,
    float* __restrict__ out) {
  const int wv = threadIdx.x >> 6, ln = threadIdx.x & 63;
  const int lr = ln & 15, lg = ln >> 4;
  const int n0 = blockIdx.x * 128;
  const int m0 = wv * 64;

  short8 afr[4][4];
#pragma unroll
  for (int mf = 0; mf < 4; mf++) {
    const ushort* ab = GHT_bf + (size_t)(m0 + mf * 16 + lr) * 128 + lg * 8;
#pragma unroll
    for (int kf = 0; kf < 4; kf++) afr[mf][kf] = *(const short8*)(ab + kf * 32);
  }

  f32x4 acc[4][8] = {};
#pragma unroll
  for (int nf = 0; nf < 8; nf++) {
    int n = n0 + nf * 16 + lr;
    int nc = min(n, NB_NITEMS - 1);  // clamp load row; store is guarded
    const ushort* bb = embB + (size_t)nc * 128 + lg * 8;
    short8 b0_[4];
#pragma unroll
    for (int kf = 0; kf < 4; kf++) b0_[kf] = *(const short8*)(bb + kf * 32);
#pragma unroll
    for (int mf = 0; mf < 4; mf++)
#pragma unroll
      for (int kf = 0; kf < 4; kf++)
        acc[mf][nf] = __builtin_amdgcn_mfma_f32_16x16x32_bf16(
            afr[mf][kf], b0_[kf], acc[mf][nf], 0, 0, 0);
  }

#pragma unroll
  for (int mf = 0; mf < 4; mf++)
#pragma unroll
    for (int r = 0; r < 4; r++) {
      int m = m0 + mf * 16 + lg * 4 + r;
#pragma unroll
      for (int nf = 0; nf < 8; nf++) {
        int n = n0 + nf * 16 + lr;
        if (n < NB_NITEMS)
          out[(size_t)m * NB_NITEMS + n] = fmaxf(acc[mf][nf][r], 0.f);
      }
    }
}

extern "C" void kernel_launch(void* const* d_in, const int* in_sizes, int n_in,
                              void* d_out, int out_size, void* d_ws, size_t ws_size,
                              hipStream_t stream) {
  const int* h_iids = (const int*)d_in[0];
  const int* adj_e = (const int*)d_in[2];
  const int* adj_r = (const int*)d_in[3];
  const float* item_emb = (const float*)d_in[4];
  const float* rel_emb = (const float*)d_in[5];
  const float* Wa = (const float*)d_in[6];
  const float* Wt = (const float*)d_in[8];
  const float* bt = (const float*)d_in[9];
  const float* Wih = (const float*)d_in[10];
  const float* Whh = (const float*)d_in[11];
  const float* bih = (const float*)d_in[12];
  const float* bhh = (const float*)d_in[13];
  const float* W1 = (const float*)d_in[14];
  const float* b1 = (const float*)d_in[15];
  const float* W2 = (const float*)d_in[16];
  const float* b2 = (const float*)d_in[17];
  const float* W3 = (const float*)d_in[18];
  const float* Wtr = (const float*)d_in[19];
  const float* btr = (const float*)d_in[20];
  float* out = (float*)d_out;

  // ws layout (bytes), all 16B-aligned. ~77 MB total.
  char* w = (char*)d_ws;
  uint* EMB_BF = (uint*)w;                    w += 25600000;  // 100000x128 bf16
  uint* REL_BF = (uint*)w;                    w += 51200;     // 200x128 bf16
  ushort* WtT_bf = (ushort*)w;                w += 32768;     // [128][128]
  ushort* WihT_bf = (ushort*)w;               w += 98304;     // [384][128] scaled
  ushort* WhhT_bf = (ushort*)w;               w += 98304;     // [384][128] scaled
  ushort* W2T_bf = (ushort*)w;                w += 32768;     // [128][128]
  float* GIBIAS = (float*)w;                  w += 2048;      // 384 floats
  int* E0 = (int*)w;                          w += 409600;    // 102400 ints
  uint* NEIB_bf = (uint*)w;                   w += 26214400;  // 102400x128 bf16
  float* GI = (float*)w;                      w += 19660800;  // 12800x384 fp32
  ushort* OUTB = (ushort*)w;                  w += 3276800;   // 12800x128 bf16
  ushort* GHT_bf = (ushort*)w;                w += 65536;

  // ---- fused prep (1 launch; +400 blocks for E0 ids) ----
  prep_kernel<<<7177, 256, 0, stream>>>(item_emb, rel_emb, Wt, Wih, Whh, W2,
                                        bih, bhh, h_iids, adj_e, EMB_BF, REL_BF,
                                        WtT_bf, WihT_bf, WhhT_bf, W2T_bf,
                                        GIBIAS, E0);

  // ---- KG hops (hop0+Wt fused; hop1+Wt+Wih fused) ----
  hoplin_kernel<<<6400, 256, 0, stream>>>(E0, adj_e, adj_r, EMB_BF, REL_BF,
                                          Wa, WtT_bf, bt, (ushort*)NEIB_bf);
  hopgi_kernel<<<800, 256, 0, stream>>>(h_iids, adj_e, adj_r, EMB_BF, REL_BF,
                                        NEIB_bf, Wa, WtT_bf, bt, WihT_bf,
                                        GIBIAS, GI);

  // ---- GRU + fused pooling ----
  gru_mfma_kernel<<<16, 512, 0, stream>>>(GI, WhhT_bf, bhh, OUTB);
  pool_kernel<<<256, 256, 0, stream>>>(h_iids, OUTB, W1, b1, W2T_bf, b2, W3,
                                       Wtr, btr, GHT_bf);

  // ---- logits ----
  logits_mfma_kernel<<<782, 256, 0, stream>>>(GHT_bf, (const ushort*)EMB_BF, out);
}